// Round 1
// 623.439 us; speedup vs baseline: 1.3558x; 1.3558x over previous
//
#include <hip/hip_runtime.h>
#include <hip/hip_bf16.h>
#include <stdint.h>

#define NN  100000
#define NME 400000
#define NWE 200000
// D = 128, 3D = 384

typedef __bf16 bf16;
typedef __bf16 bf16x8 __attribute__((ext_vector_type(8)));
typedef float  f32x4  __attribute__((ext_vector_type(4)));

static __device__ __forceinline__ bf16 f2bf(float f) {
    union { unsigned int i; float f; } v; v.f = f;
    unsigned int r = (v.i + 0x7fffu + ((v.i >> 16) & 1u)) >> 16;
    union { unsigned short s; bf16 b; } u; u.s = (unsigned short)r;
    return u.b;
}

// ---------------------------------------------------------------------------
// Weight prep: read fp32 W1 (384x128), W2, W3 (128x128); write transposed bf16
// so the MFMA B-fragment (8 consecutive k for fixed n) is a contiguous 16B load.
// ---------------------------------------------------------------------------
__global__ void prep_weights(const float* __restrict__ W1, const float* __restrict__ W2,
                             const float* __restrict__ W3, bf16* __restrict__ W1t,
                             bf16* __restrict__ W2t, bf16* __restrict__ W3t) {
    int tid = blockIdx.x * 256 + threadIdx.x;
    if (tid < 49152) {                    // W1: k in [0,384), n in [0,128)
        int k = tid >> 7, n = tid & 127;
        W1t[n * 384 + k] = f2bf(W1[tid]);
    } else if (tid < 65536) {
        int t2 = tid - 49152;
        int k = t2 >> 7, n = t2 & 127;
        W2t[n * 128 + k] = f2bf(W2[t2]);
    } else if (tid < 81920) {
        int t2 = tid - 65536;
        int k = t2 >> 7, n = t2 & 127;
        W3t[n * 128 + k] = f2bf(W3[t2]);
    }
}

// ---------------------------------------------------------------------------
// CSR build, step 1: per-receiver degree histogram (int atomics, tiny traffic).
// ---------------------------------------------------------------------------
__global__ __launch_bounds__(256) void count_edges(const int* __restrict__ mrecv,
                                                   const int* __restrict__ wrecv,
                                                   int* __restrict__ mdeg,
                                                   int* __restrict__ wdeg) {
    int t = blockIdx.x * 256 + threadIdx.x;
    if (t < NME) {
        atomicAdd(mdeg + mrecv[t], 1);
    } else {
        int t2 = t - NME;
        if (t2 < NWE) atomicAdd(wdeg + wrecv[t2], 1);
    }
}

// ---------------------------------------------------------------------------
// CSR build, step 2a: per-block partial sums. 25 blocks per segment, each
// covering a 4096-int window with coalesced int4 loads. Replaces the old
// 2-workgroup scan_deg (232 us, 0.3% occupancy) with a saturating pass.
// ---------------------------------------------------------------------------
__global__ __launch_bounds__(256) void scan_part(const int* __restrict__ mdeg,
                                                 const int* __restrict__ wdeg,
                                                 int* __restrict__ bsum) {
    const int nblk = 25;                      // ceil(100000 / 4096)
    int seg = blockIdx.x / nblk;
    int blk = blockIdx.x % nblk;
    const int* deg = (seg == 0) ? mdeg : wdeg;
    const int t = threadIdx.x;
    const int base = blk * 4096;
    int sum = 0;
#pragma unroll
    for (int i = 0; i < 4; ++i) {
        int idx = base + (i * 256 + t) * 4;   // 16B-aligned; NN % 4 == 0
        if (idx < NN) {
            int4 v = *(const int4*)(deg + idx);
            sum += v.x + v.y + v.z + v.w;
        }
    }
#pragma unroll
    for (int m = 1; m < 64; m <<= 1) sum += __shfl_xor(sum, m, 64);
    __shared__ int ssum[4];
    if ((t & 63) == 0) ssum[t >> 6] = sum;
    __syncthreads();
    if (t == 0) bsum[blockIdx.x] = ssum[0] + ssum[1] + ssum[2] + ssum[3];
}

// ---------------------------------------------------------------------------
// CSR build, step 2b: block-local exclusive scan + block offset, writes
// off (in place over deg) and cur. Thread 0 folds the <=24 preceding block
// sums of its segment (50 ints total -- trivial).
// ---------------------------------------------------------------------------
__global__ __launch_bounds__(256) void scan_write(int* __restrict__ mdeg, int* __restrict__ wdeg,
                                                  int* __restrict__ mcur, int* __restrict__ wcur,
                                                  const int* __restrict__ bsum) {
    __shared__ int sprefix;
    __shared__ int sscan[256];
    const int nblk = 25;
    int seg = blockIdx.x / nblk;
    int blk = blockIdx.x % nblk;
    int* deg = (seg == 0) ? mdeg : wdeg;
    int* cur = (seg == 0) ? mcur : wcur;
    const int t = threadIdx.x;
    if (t == 0) {
        int s = 0;
        const int* bs = bsum + seg * nblk;
        for (int i = 0; i < blk; ++i) s += bs[i];
        sprefix = s;
    }
    const int base = blk * 4096 + t * 16;
    int v[16];
#pragma unroll
    for (int i = 0; i < 16; i += 4) {
        int idx = base + i;                   // 16B-aligned; NN % 4 == 0
        if (idx < NN) {
            int4 q = *(const int4*)(deg + idx);
            v[i] = q.x; v[i + 1] = q.y; v[i + 2] = q.z; v[i + 3] = q.w;
        } else {
            v[i] = v[i + 1] = v[i + 2] = v[i + 3] = 0;
        }
    }
    int lsum = 0;
#pragma unroll
    for (int i = 0; i < 16; ++i) lsum += v[i];
    sscan[t] = lsum;
    __syncthreads();
    for (int d = 1; d < 256; d <<= 1) {       // inclusive scan of thread sums
        int vv = (t >= d) ? sscan[t - d] : 0;
        __syncthreads();
        sscan[t] += vv;
        __syncthreads();
    }
    int run = sprefix + sscan[t] - lsum;      // exclusive prefix for this thread
#pragma unroll
    for (int i = 0; i < 16; i += 4) {
        int idx = base + i;
        if (idx < NN) {
            int4 o;
            o.x = run; run += v[i];
            o.y = run; run += v[i + 1];
            o.z = run; run += v[i + 2];
            o.w = run; run += v[i + 3];
            *(int4*)(deg + idx) = o;
            *(int4*)(cur + idx) = o;
        }
    }
}

// ---------------------------------------------------------------------------
// CSR build, step 3: bucket edge ids by receiver (cursor atomics).
// ---------------------------------------------------------------------------
__global__ __launch_bounds__(256) void fill_lists(const int* __restrict__ mrecv,
                                                  const int* __restrict__ wrecv,
                                                  int* __restrict__ mcur, int* __restrict__ wcur,
                                                  int* __restrict__ mlist, int* __restrict__ wlist) {
    int t = blockIdx.x * 256 + threadIdx.x;
    if (t < NME) {
        int r = mrecv[t];
        int p = atomicAdd(mcur + r, 1);
        mlist[p] = t;
    } else {
        int t2 = t - NME;
        if (t2 < NWE) {
            int r = wrecv[t2];
            int p = atomicAdd(wcur + r, 1);
            wlist[p] = t2;
        }
    }
}

// ---------------------------------------------------------------------------
// Gather: quarter-wave (16 lanes) per node; lane g sums floats [g*8, g*8+8)
// across the node's incoming edges (fp32 accum), writes bf16 agg row once.
// No float atomics, no RMW write amplification.
// ---------------------------------------------------------------------------
__global__ __launch_bounds__(256) void gather_sum(const float* __restrict__ attr,
                                                  const int* __restrict__ off,
                                                  const int* __restrict__ list,
                                                  bf16* __restrict__ agg, int nE) {
    int t = blockIdx.x * 256 + threadIdx.x;
    int node = t >> 4;
    int g = t & 15;
    if (node >= NN) return;
    int j0 = off[node];
    int j1 = (node == NN - 1) ? nE : off[node + 1];
    f32x4 lo = (f32x4)0.0f, hi = (f32x4)0.0f;
    for (int j = j0; j < j1; ++j) {
        int e = list[j];
        const float* src = attr + (size_t)e * 128 + g * 8;
        f32x4 a = *(const f32x4*)(src);
        f32x4 b = *(const f32x4*)(src + 4);
        lo += a;
        hi += b;
    }
    bf16x8 o;
#pragma unroll
    for (int i = 0; i < 4; ++i) {
        o[i]     = f2bf(lo[i]);
        o[4 + i] = f2bf(hi[i]);
    }
    *(bf16x8*)(agg + (size_t)node * 128 + g * 8) = o;
}

// ---------------------------------------------------------------------------
// Fused node MLP + LayerNorm.
// Block = 256 threads = 4 waves; each wave owns a 16-node strip (M=16, N=128).
// Layer1: K=384 over [x (fp32->bf16) | mesh_agg (bf16) | world_agg (bf16)];
// Layers 2/3: K=128 with LDS round-trip (C-layout -> A-layout).
// LayerNorm via 16-lane xor-shuffles. fp32 output.
// ---------------------------------------------------------------------------
__global__ __launch_bounds__(256) void node_mlp(
    const float* __restrict__ x, const bf16* __restrict__ magg,
    const bf16* __restrict__ wagg, const bf16* __restrict__ W1t,
    const bf16* __restrict__ W2t, const bf16* __restrict__ W3t,
    const float* __restrict__ b1, const float* __restrict__ b2,
    const float* __restrict__ b3, const float* __restrict__ gam,
    const float* __restrict__ bet, float* __restrict__ out) {
    __shared__ bf16 sh[4 * 16 * 136];  // per-wave 16x(128+8) bf16; row stride 272B = 17*16B
    const int wave = threadIdx.x >> 6;
    const int lane = threadIdx.x & 63;
    const int quad = lane >> 4;
    const int l16 = lane & 15;
    const int node_base = blockIdx.x * 64 + wave * 16;
    bf16* shw = sh + wave * (16 * 136);

    int arow = node_base + l16;
    if (arow >= NN) arow = NN - 1;  // clamp; stores are guarded

    // ---- Layer 1: [16 x 384] @ [384 x 128] ----
    f32x4 acc[8];
#pragma unroll
    for (int t = 0; t < 8; ++t) acc[t] = (f32x4)0.0f;

#pragma unroll
    for (int ks = 0; ks < 12; ++ks) {
        int kg = ks * 32 + quad * 8;  // this lane's k-base in [0,384)
        bf16x8 afrag;
        if (kg < 128) {
            const float* src = x + (size_t)arow * 128 + kg;
            f32x4 lo = *(const f32x4*)(src);
            f32x4 hi = *(const f32x4*)(src + 4);
#pragma unroll
            for (int i = 0; i < 4; ++i) {
                afrag[i]     = f2bf(lo[i]);
                afrag[4 + i] = f2bf(hi[i]);
            }
        } else if (kg < 256) {
            afrag = *(const bf16x8*)(magg + (size_t)arow * 128 + (kg - 128));
        } else {
            afrag = *(const bf16x8*)(wagg + (size_t)arow * 128 + (kg - 256));
        }
#pragma unroll
        for (int t = 0; t < 8; ++t) {
            bf16x8 bfrag = *(const bf16x8*)(W1t + (t * 16 + l16) * 384 + ks * 32 + quad * 8);
            acc[t] = __builtin_amdgcn_mfma_f32_16x16x32_bf16(afrag, bfrag, acc[t], 0, 0, 0);
        }
    }
    // bias + relu, C-layout -> LDS (bf16)
#pragma unroll
    for (int t = 0; t < 8; ++t) {
        float bv = b1[t * 16 + l16];
#pragma unroll
        for (int r = 0; r < 4; ++r) {
            float h = acc[t][r] + bv;
            h = h > 0.0f ? h : 0.0f;
            shw[(quad * 4 + r) * 136 + t * 16 + l16] = f2bf(h);
        }
    }
    __syncthreads();

    // ---- Layer 2: [16 x 128] @ [128 x 128] ----
    bf16x8 a2[4];
#pragma unroll
    for (int ks = 0; ks < 4; ++ks)
        a2[ks] = *(const bf16x8*)(shw + l16 * 136 + ks * 32 + quad * 8);
#pragma unroll
    for (int t = 0; t < 8; ++t) acc[t] = (f32x4)0.0f;
#pragma unroll
    for (int ks = 0; ks < 4; ++ks) {
#pragma unroll
        for (int t = 0; t < 8; ++t) {
            bf16x8 bfrag = *(const bf16x8*)(W2t + (t * 16 + l16) * 128 + ks * 32 + quad * 8);
            acc[t] = __builtin_amdgcn_mfma_f32_16x16x32_bf16(a2[ks], bfrag, acc[t], 0, 0, 0);
        }
    }
    __syncthreads();
#pragma unroll
    for (int t = 0; t < 8; ++t) {
        float bv = b2[t * 16 + l16];
#pragma unroll
        for (int r = 0; r < 4; ++r) {
            float h = acc[t][r] + bv;
            h = h > 0.0f ? h : 0.0f;
            shw[(quad * 4 + r) * 136 + t * 16 + l16] = f2bf(h);
        }
    }
    __syncthreads();

    // ---- Layer 3: [16 x 128] @ [128 x 128] (no relu) ----
#pragma unroll
    for (int ks = 0; ks < 4; ++ks)
        a2[ks] = *(const bf16x8*)(shw + l16 * 136 + ks * 32 + quad * 8);
#pragma unroll
    for (int t = 0; t < 8; ++t) acc[t] = (f32x4)0.0f;
#pragma unroll
    for (int ks = 0; ks < 4; ++ks) {
#pragma unroll
        for (int t = 0; t < 8; ++t) {
            bf16x8 bfrag = *(const bf16x8*)(W3t + (t * 16 + l16) * 128 + ks * 32 + quad * 8);
            acc[t] = __builtin_amdgcn_mfma_f32_16x16x32_bf16(a2[ks], bfrag, acc[t], 0, 0, 0);
        }
    }
    // add b3
#pragma unroll
    for (int t = 0; t < 8; ++t) {
        float bv = b3[t * 16 + l16];
#pragma unroll
        for (int r = 0; r < 4; ++r) acc[t][r] += bv;
    }

    // ---- LayerNorm over the 128 cols of each row ----
    float gv[8], bv2[8];
#pragma unroll
    for (int t = 0; t < 8; ++t) {
        gv[t]  = gam[t * 16 + l16];
        bv2[t] = bet[t * 16 + l16];
    }
    float mean[4], rstd[4];
#pragma unroll
    for (int r = 0; r < 4; ++r) {
        float s = 0.0f, s2 = 0.0f;
#pragma unroll
        for (int t = 0; t < 8; ++t) {
            float v = acc[t][r];
            s += v;
            s2 += v * v;
        }
#pragma unroll
        for (int m = 1; m < 16; m <<= 1) {
            s  += __shfl_xor(s, m, 64);
            s2 += __shfl_xor(s2, m, 64);
        }
        float mu = s * (1.0f / 128.0f);
        float var = s2 * (1.0f / 128.0f) - mu * mu;
        mean[r] = mu;
        rstd[r] = rsqrtf(var + 1e-5f);
    }
#pragma unroll
    for (int r = 0; r < 4; ++r) {
        int row = node_base + quad * 4 + r;
        if (row < NN) {
#pragma unroll
            for (int t = 0; t < 8; ++t) {
                float o = (acc[t][r] - mean[r]) * rstd[r] * gv[t] + bv2[t];
                out[(size_t)row * 128 + t * 16 + l16] = o;
            }
        }
    }
}

// ---------------------------------------------------------------------------
extern "C" void kernel_launch(void* const* d_in, const int* in_sizes, int n_in,
                              void* d_out, int out_size, void* d_ws, size_t ws_size,
                              hipStream_t stream) {
    const float* x   = (const float*)d_in[0];
    const float* ea  = (const float*)d_in[1];
    const int*   ei  = (const int*)d_in[2];   // (2, NME) flat; recv row at offset NME
    const float* wea = (const float*)d_in[3];
    const int*   wei = (const int*)d_in[4];   // (2, NWE) flat; recv row at offset NWE
    const float* W1  = (const float*)d_in[5];
    const float* b1  = (const float*)d_in[6];
    const float* W2  = (const float*)d_in[7];
    const float* b2  = (const float*)d_in[8];
    const float* W3  = (const float*)d_in[9];
    const float* b3  = (const float*)d_in[10];
    const float* gam = (const float*)d_in[11];
    const float* bet = (const float*)d_in[12];

    char* ws = (char*)d_ws;
    bf16* magg = (bf16*)(ws);                      // 25,600,000 B
    bf16* wagg = (bf16*)(ws + 25600000);           // 25,600,000 B
    bf16* W1t  = (bf16*)(ws + 51200000);           // 98,304 B
    bf16* W2t  = (bf16*)(ws + 51298304);           // 32,768 B
    bf16* W3t  = (bf16*)(ws + 51331072);           // 32,768 B
    int*  mdeg = (int*)(ws + 51363840);            // 400,000 B (deg -> off in place)
    int*  wdeg = (int*)(ws + 51763840);            // 400,000 B (contiguous with mdeg)
    int*  mcur = (int*)(ws + 52163840);            // 400,000 B
    int*  wcur = (int*)(ws + 52563840);            // 400,000 B
    int*  mlist = (int*)(ws + 52963840);           // 1,600,000 B
    int*  wlist = (int*)(ws + 54563840);           // 800,000 B
    int*  bsum  = (int*)(ws + 55363840);           // 200 B (50 block partial sums)

    // zero only the two degree arrays (contiguous 800 KB)
    hipMemsetAsync(ws + 51363840, 0, 800000, stream);

    prep_weights<<<320, 256, 0, stream>>>(W1, W2, W3, W1t, W2t, W3t);

    count_edges<<<(NME + NWE + 255) / 256, 256, 0, stream>>>(ei + NME, wei + NWE, mdeg, wdeg);
    scan_part<<<50, 256, 0, stream>>>(mdeg, wdeg, bsum);
    scan_write<<<50, 256, 0, stream>>>(mdeg, wdeg, mcur, wcur, bsum);
    fill_lists<<<(NME + NWE + 255) / 256, 256, 0, stream>>>(ei + NME, wei + NWE,
                                                            mcur, wcur, mlist, wlist);

    gather_sum<<<(NN * 16 + 255) / 256, 256, 0, stream>>>(ea, mdeg, mlist, magg, NME);
    gather_sum<<<(NN * 16 + 255) / 256, 256, 0, stream>>>(wea, wdeg, wlist, wagg, NWE);

    node_mlp<<<(NN + 63) / 64, 256, 0, stream>>>(x, magg, wagg, W1t, W2t, W3t,
                                                 b1, b2, b3, gam, bet, (float*)d_out);
}

// Round 2
// 603.252 us; speedup vs baseline: 1.4012x; 1.0335x over previous
//
#include <hip/hip_runtime.h>
#include <hip/hip_bf16.h>
#include <stdint.h>

#define NN  100000
#define NME 400000
#define NWE 200000
// D = 128, 3D = 384

typedef __bf16 bf16;
typedef __bf16 bf16x8 __attribute__((ext_vector_type(8)));
typedef float  f32x4  __attribute__((ext_vector_type(4)));

static __device__ __forceinline__ bf16 f2bf(float f) {
    union { unsigned int i; float f; } v; v.f = f;
    unsigned int r = (v.i + 0x7fffu + ((v.i >> 16) & 1u)) >> 16;
    union { unsigned short s; bf16 b; } u; u.s = (unsigned short)r;
    return u.b;
}

// ---------------------------------------------------------------------------
// Weight prep: read fp32 W1 (384x128), W2, W3 (128x128); write transposed bf16
// so the MFMA B-fragment (8 consecutive k for fixed n) is a contiguous 16B load.
// ---------------------------------------------------------------------------
__global__ void prep_weights(const float* __restrict__ W1, const float* __restrict__ W2,
                             const float* __restrict__ W3, bf16* __restrict__ W1t,
                             bf16* __restrict__ W2t, bf16* __restrict__ W3t) {
    int tid = blockIdx.x * 256 + threadIdx.x;
    if (tid < 49152) {                    // W1: k in [0,384), n in [0,128)
        int k = tid >> 7, n = tid & 127;
        W1t[n * 384 + k] = f2bf(W1[tid]);
    } else if (tid < 65536) {
        int t2 = tid - 49152;
        int k = t2 >> 7, n = t2 & 127;
        W2t[n * 128 + k] = f2bf(W2[t2]);
    } else if (tid < 81920) {
        int t2 = tid - 65536;
        int k = t2 >> 7, n = t2 & 127;
        W3t[n * 128 + k] = f2bf(W3[t2]);
    }
}

// ---------------------------------------------------------------------------
// CSR build, step 1: per-receiver degree histogram (int atomics, tiny traffic).
// ---------------------------------------------------------------------------
__global__ __launch_bounds__(256) void count_edges(const int* __restrict__ mrecv,
                                                   const int* __restrict__ wrecv,
                                                   int* __restrict__ mdeg,
                                                   int* __restrict__ wdeg) {
    int t = blockIdx.x * 256 + threadIdx.x;
    if (t < NME) {
        atomicAdd(mdeg + mrecv[t], 1);
    } else {
        int t2 = t - NME;
        if (t2 < NWE) atomicAdd(wdeg + wrecv[t2], 1);
    }
}

// ---------------------------------------------------------------------------
// CSR build, step 2a: per-block partial sums. 25 blocks per segment, each
// covering a 4096-int window with coalesced int4 loads.
// ---------------------------------------------------------------------------
__global__ __launch_bounds__(256) void scan_part(const int* __restrict__ mdeg,
                                                 const int* __restrict__ wdeg,
                                                 int* __restrict__ bsum) {
    const int nblk = 25;                      // ceil(100000 / 4096)
    int seg = blockIdx.x / nblk;
    int blk = blockIdx.x % nblk;
    const int* deg = (seg == 0) ? mdeg : wdeg;
    const int t = threadIdx.x;
    const int base = blk * 4096;
    int sum = 0;
#pragma unroll
    for (int i = 0; i < 4; ++i) {
        int idx = base + (i * 256 + t) * 4;   // 16B-aligned; NN % 4 == 0
        if (idx < NN) {
            int4 v = *(const int4*)(deg + idx);
            sum += v.x + v.y + v.z + v.w;
        }
    }
#pragma unroll
    for (int m = 1; m < 64; m <<= 1) sum += __shfl_xor(sum, m, 64);
    __shared__ int ssum[4];
    if ((t & 63) == 0) ssum[t >> 6] = sum;
    __syncthreads();
    if (t == 0) bsum[blockIdx.x] = ssum[0] + ssum[1] + ssum[2] + ssum[3];
}

// ---------------------------------------------------------------------------
// CSR build, step 2b: block-local exclusive scan + block offset, writes
// off (in place over deg) and cur.
// ---------------------------------------------------------------------------
__global__ __launch_bounds__(256) void scan_write(int* __restrict__ mdeg, int* __restrict__ wdeg,
                                                  int* __restrict__ mcur, int* __restrict__ wcur,
                                                  const int* __restrict__ bsum) {
    __shared__ int sprefix;
    __shared__ int sscan[256];
    const int nblk = 25;
    int seg = blockIdx.x / nblk;
    int blk = blockIdx.x % nblk;
    int* deg = (seg == 0) ? mdeg : wdeg;
    int* cur = (seg == 0) ? mcur : wcur;
    const int t = threadIdx.x;
    if (t == 0) {
        int s = 0;
        const int* bs = bsum + seg * nblk;
        for (int i = 0; i < blk; ++i) s += bs[i];
        sprefix = s;
    }
    const int base = blk * 4096 + t * 16;
    int v[16];
#pragma unroll
    for (int i = 0; i < 16; i += 4) {
        int idx = base + i;                   // 16B-aligned; NN % 4 == 0
        if (idx < NN) {
            int4 q = *(const int4*)(deg + idx);
            v[i] = q.x; v[i + 1] = q.y; v[i + 2] = q.z; v[i + 3] = q.w;
        } else {
            v[i] = v[i + 1] = v[i + 2] = v[i + 3] = 0;
        }
    }
    int lsum = 0;
#pragma unroll
    for (int i = 0; i < 16; ++i) lsum += v[i];
    sscan[t] = lsum;
    __syncthreads();
    for (int d = 1; d < 256; d <<= 1) {       // inclusive scan of thread sums
        int vv = (t >= d) ? sscan[t - d] : 0;
        __syncthreads();
        sscan[t] += vv;
        __syncthreads();
    }
    int run = sprefix + sscan[t] - lsum;      // exclusive prefix for this thread
#pragma unroll
    for (int i = 0; i < 16; i += 4) {
        int idx = base + i;
        if (idx < NN) {
            int4 o;
            o.x = run; run += v[i];
            o.y = run; run += v[i + 1];
            o.z = run; run += v[i + 2];
            o.w = run; run += v[i + 3];
            *(int4*)(deg + idx) = o;
            *(int4*)(cur + idx) = o;
        }
    }
}

// ---------------------------------------------------------------------------
// CSR build, step 3: bucket edge ids by receiver (cursor atomics).
// ---------------------------------------------------------------------------
__global__ __launch_bounds__(256) void fill_lists(const int* __restrict__ mrecv,
                                                  const int* __restrict__ wrecv,
                                                  int* __restrict__ mcur, int* __restrict__ wcur,
                                                  int* __restrict__ mlist, int* __restrict__ wlist) {
    int t = blockIdx.x * 256 + threadIdx.x;
    if (t < NME) {
        int r = mrecv[t];
        int p = atomicAdd(mcur + r, 1);
        mlist[p] = t;
    } else {
        int t2 = t - NME;
        if (t2 < NWE) {
            int r = wrecv[t2];
            int p = atomicAdd(wcur + r, 1);
            wlist[p] = t2;
        }
    }
}

// ---------------------------------------------------------------------------
// Gather: quarter-wave (16 lanes) per node; lane g sums floats [g*8, g*8+8)
// across the node's incoming edges (fp32 accum), writes bf16 agg row once.
// ---------------------------------------------------------------------------
__global__ __launch_bounds__(256) void gather_sum(const float* __restrict__ attr,
                                                  const int* __restrict__ off,
                                                  const int* __restrict__ list,
                                                  bf16* __restrict__ agg, int nE) {
    int t = blockIdx.x * 256 + threadIdx.x;
    int node = t >> 4;
    int g = t & 15;
    if (node >= NN) return;
    int j0 = off[node];
    int j1 = (node == NN - 1) ? nE : off[node + 1];
    f32x4 lo = (f32x4)0.0f, hi = (f32x4)0.0f;
    for (int j = j0; j < j1; ++j) {
        int e = list[j];
        const float* src = attr + (size_t)e * 128 + g * 8;
        f32x4 a = *(const f32x4*)(src);
        f32x4 b = *(const f32x4*)(src + 4);
        lo += a;
        hi += b;
    }
    bf16x8 o;
#pragma unroll
    for (int i = 0; i < 4; ++i) {
        o[i]     = f2bf(lo[i]);
        o[4 + i] = f2bf(hi[i]);
    }
    *(bf16x8*)(agg + (size_t)node * 128 + g * 8) = o;
}

// ---------------------------------------------------------------------------
// Fused node MLP + LayerNorm, M=32 per wave.
// Block = 256 threads = 4 waves; each wave owns a 32-node strip (two 16-row
// A-fragments share every B-fragment -> 2 MFMA per 16B weight load, and half
// the per-wave weight refetch of the M=16 version).
// Layer1: K=384 over [x (fp32->bf16) | mesh_agg (bf16) | world_agg (bf16)];
// Layers 2/3: K=128 with LDS round-trip (C-layout -> A-layout).
// LayerNorm via 16-lane xor-shuffles. fp32 output.
// ---------------------------------------------------------------------------
__global__ __launch_bounds__(256) void node_mlp(
    const float* __restrict__ x, const bf16* __restrict__ magg,
    const bf16* __restrict__ wagg, const bf16* __restrict__ W1t,
    const bf16* __restrict__ W2t, const bf16* __restrict__ W3t,
    const float* __restrict__ b1, const float* __restrict__ b2,
    const float* __restrict__ b3, const float* __restrict__ gam,
    const float* __restrict__ bet, float* __restrict__ out) {
    __shared__ bf16 sh[4 * 32 * 136];  // per-wave 32x(128+8) bf16 tile
    const int wave = threadIdx.x >> 6;
    const int lane = threadIdx.x & 63;
    const int quad = lane >> 4;
    const int l16 = lane & 15;
    const int node_base = blockIdx.x * 128 + wave * 32;
    bf16* shw = sh + wave * (32 * 136);

    int arow[2];
    arow[0] = node_base + l16;
    arow[1] = node_base + 16 + l16;
    if (arow[0] >= NN) arow[0] = NN - 1;  // clamp; stores are guarded
    if (arow[1] >= NN) arow[1] = NN - 1;

    // ---- Layer 1: [32 x 384] @ [384 x 128] ----
    f32x4 acc[2][8];
#pragma unroll
    for (int rg = 0; rg < 2; ++rg)
#pragma unroll
        for (int t = 0; t < 8; ++t) acc[rg][t] = (f32x4)0.0f;

#pragma unroll
    for (int ks = 0; ks < 12; ++ks) {
        int kg = ks * 32 + quad * 8;  // this lane's k-base in [0,384)
        bf16x8 af[2];
#pragma unroll
        for (int rg = 0; rg < 2; ++rg) {
            if (ks < 4) {
                const float* src = x + (size_t)arow[rg] * 128 + kg;
                f32x4 lo = *(const f32x4*)(src);
                f32x4 hi = *(const f32x4*)(src + 4);
#pragma unroll
                for (int i = 0; i < 4; ++i) {
                    af[rg][i]     = f2bf(lo[i]);
                    af[rg][4 + i] = f2bf(hi[i]);
                }
            } else if (ks < 8) {
                af[rg] = *(const bf16x8*)(magg + (size_t)arow[rg] * 128 + (kg - 128));
            } else {
                af[rg] = *(const bf16x8*)(wagg + (size_t)arow[rg] * 128 + (kg - 256));
            }
        }
#pragma unroll
        for (int t = 0; t < 8; ++t) {
            bf16x8 bfrag = *(const bf16x8*)(W1t + (t * 16 + l16) * 384 + ks * 32 + quad * 8);
            acc[0][t] = __builtin_amdgcn_mfma_f32_16x16x32_bf16(af[0], bfrag, acc[0][t], 0, 0, 0);
            acc[1][t] = __builtin_amdgcn_mfma_f32_16x16x32_bf16(af[1], bfrag, acc[1][t], 0, 0, 0);
        }
    }
    // bias + relu, C-layout -> LDS (bf16)
#pragma unroll
    for (int t = 0; t < 8; ++t) {
        float bv = b1[t * 16 + l16];
#pragma unroll
        for (int rg = 0; rg < 2; ++rg)
#pragma unroll
            for (int r = 0; r < 4; ++r) {
                float h = acc[rg][t][r] + bv;
                h = h > 0.0f ? h : 0.0f;
                shw[(rg * 16 + quad * 4 + r) * 136 + t * 16 + l16] = f2bf(h);
            }
    }
    __syncthreads();

    // ---- Layer 2: [32 x 128] @ [128 x 128] ----
    bf16x8 a2[2][4];
#pragma unroll
    for (int rg = 0; rg < 2; ++rg)
#pragma unroll
        for (int ks = 0; ks < 4; ++ks)
            a2[rg][ks] = *(const bf16x8*)(shw + (rg * 16 + l16) * 136 + ks * 32 + quad * 8);
#pragma unroll
    for (int rg = 0; rg < 2; ++rg)
#pragma unroll
        for (int t = 0; t < 8; ++t) acc[rg][t] = (f32x4)0.0f;
#pragma unroll
    for (int ks = 0; ks < 4; ++ks) {
#pragma unroll
        for (int t = 0; t < 8; ++t) {
            bf16x8 bfrag = *(const bf16x8*)(W2t + (t * 16 + l16) * 128 + ks * 32 + quad * 8);
            acc[0][t] = __builtin_amdgcn_mfma_f32_16x16x32_bf16(a2[0][ks], bfrag, acc[0][t], 0, 0, 0);
            acc[1][t] = __builtin_amdgcn_mfma_f32_16x16x32_bf16(a2[1][ks], bfrag, acc[1][t], 0, 0, 0);
        }
    }
    __syncthreads();
#pragma unroll
    for (int t = 0; t < 8; ++t) {
        float bv = b2[t * 16 + l16];
#pragma unroll
        for (int rg = 0; rg < 2; ++rg)
#pragma unroll
            for (int r = 0; r < 4; ++r) {
                float h = acc[rg][t][r] + bv;
                h = h > 0.0f ? h : 0.0f;
                shw[(rg * 16 + quad * 4 + r) * 136 + t * 16 + l16] = f2bf(h);
            }
    }
    __syncthreads();

    // ---- Layer 3: [32 x 128] @ [128 x 128] (no relu) ----
#pragma unroll
    for (int rg = 0; rg < 2; ++rg)
#pragma unroll
        for (int ks = 0; ks < 4; ++ks)
            a2[rg][ks] = *(const bf16x8*)(shw + (rg * 16 + l16) * 136 + ks * 32 + quad * 8);
#pragma unroll
    for (int rg = 0; rg < 2; ++rg)
#pragma unroll
        for (int t = 0; t < 8; ++t) acc[rg][t] = (f32x4)0.0f;
#pragma unroll
    for (int ks = 0; ks < 4; ++ks) {
#pragma unroll
        for (int t = 0; t < 8; ++t) {
            bf16x8 bfrag = *(const bf16x8*)(W3t + (t * 16 + l16) * 128 + ks * 32 + quad * 8);
            acc[0][t] = __builtin_amdgcn_mfma_f32_16x16x32_bf16(a2[0][ks], bfrag, acc[0][t], 0, 0, 0);
            acc[1][t] = __builtin_amdgcn_mfma_f32_16x16x32_bf16(a2[1][ks], bfrag, acc[1][t], 0, 0, 0);
        }
    }
    // add b3
#pragma unroll
    for (int t = 0; t < 8; ++t) {
        float bv = b3[t * 16 + l16];
#pragma unroll
        for (int rg = 0; rg < 2; ++rg)
#pragma unroll
            for (int r = 0; r < 4; ++r) acc[rg][t][r] += bv;
    }

    // ---- LayerNorm over the 128 cols of each row ----
    float gv[8], bv2[8];
#pragma unroll
    for (int t = 0; t < 8; ++t) {
        gv[t]  = gam[t * 16 + l16];
        bv2[t] = bet[t * 16 + l16];
    }
#pragma unroll
    for (int rg = 0; rg < 2; ++rg) {
        float mean[4], rstd[4];
#pragma unroll
        for (int r = 0; r < 4; ++r) {
            float s = 0.0f, s2 = 0.0f;
#pragma unroll
            for (int t = 0; t < 8; ++t) {
                float v = acc[rg][t][r];
                s += v;
                s2 += v * v;
            }
#pragma unroll
            for (int m = 1; m < 16; m <<= 1) {
                s  += __shfl_xor(s, m, 64);
                s2 += __shfl_xor(s2, m, 64);
            }
            float mu = s * (1.0f / 128.0f);
            float var = s2 * (1.0f / 128.0f) - mu * mu;
            mean[r] = mu;
            rstd[r] = rsqrtf(var + 1e-5f);
        }
#pragma unroll
        for (int r = 0; r < 4; ++r) {
            int row = node_base + rg * 16 + quad * 4 + r;
            if (row < NN) {
#pragma unroll
                for (int t = 0; t < 8; ++t) {
                    float o = (acc[rg][t][r] - mean[r]) * rstd[r] * gv[t] + bv2[t];
                    out[(size_t)row * 128 + t * 16 + l16] = o;
                }
            }
        }
    }
}

// ---------------------------------------------------------------------------
extern "C" void kernel_launch(void* const* d_in, const int* in_sizes, int n_in,
                              void* d_out, int out_size, void* d_ws, size_t ws_size,
                              hipStream_t stream) {
    const float* x   = (const float*)d_in[0];
    const float* ea  = (const float*)d_in[1];
    const int*   ei  = (const int*)d_in[2];   // (2, NME) flat; recv row at offset NME
    const float* wea = (const float*)d_in[3];
    const int*   wei = (const int*)d_in[4];   // (2, NWE) flat; recv row at offset NWE
    const float* W1  = (const float*)d_in[5];
    const float* b1  = (const float*)d_in[6];
    const float* W2  = (const float*)d_in[7];
    const float* b2  = (const float*)d_in[8];
    const float* W3  = (const float*)d_in[9];
    const float* b3  = (const float*)d_in[10];
    const float* gam = (const float*)d_in[11];
    const float* bet = (const float*)d_in[12];

    char* ws = (char*)d_ws;
    bf16* magg = (bf16*)(ws);                      // 25,600,000 B
    bf16* wagg = (bf16*)(ws + 25600000);           // 25,600,000 B
    bf16* W1t  = (bf16*)(ws + 51200000);           // 98,304 B
    bf16* W2t  = (bf16*)(ws + 51298304);           // 32,768 B
    bf16* W3t  = (bf16*)(ws + 51331072);           // 32,768 B
    int*  mdeg = (int*)(ws + 51363840);            // 400,000 B (deg -> off in place)
    int*  wdeg = (int*)(ws + 51763840);            // 400,000 B (contiguous with mdeg)
    int*  mcur = (int*)(ws + 52163840);            // 400,000 B
    int*  wcur = (int*)(ws + 52563840);            // 400,000 B
    int*  mlist = (int*)(ws + 52963840);           // 1,600,000 B
    int*  wlist = (int*)(ws + 54563840);           // 800,000 B
    int*  bsum  = (int*)(ws + 55363840);           // 200 B (50 block partial sums)

    // zero only the two degree arrays (contiguous 800 KB)
    hipMemsetAsync(ws + 51363840, 0, 800000, stream);

    prep_weights<<<320, 256, 0, stream>>>(W1, W2, W3, W1t, W2t, W3t);

    count_edges<<<(NME + NWE + 255) / 256, 256, 0, stream>>>(ei + NME, wei + NWE, mdeg, wdeg);
    scan_part<<<50, 256, 0, stream>>>(mdeg, wdeg, bsum);
    scan_write<<<50, 256, 0, stream>>>(mdeg, wdeg, mcur, wcur, bsum);
    fill_lists<<<(NME + NWE + 255) / 256, 256, 0, stream>>>(ei + NME, wei + NWE,
                                                            mcur, wcur, mlist, wlist);

    gather_sum<<<(NN * 16 + 255) / 256, 256, 0, stream>>>(ea, mdeg, mlist, magg, NME);
    gather_sum<<<(NN * 16 + 255) / 256, 256, 0, stream>>>(wea, wdeg, wlist, wagg, NWE);

    node_mlp<<<(NN + 127) / 128, 256, 0, stream>>>(x, magg, wagg, W1t, W2t, W3t,
                                                   b1, b2, b3, gam, bet, (float*)d_out);
}

// Round 5
// 570.534 us; speedup vs baseline: 1.4816x; 1.0573x over previous
//
#include <hip/hip_runtime.h>
#include <hip/hip_bf16.h>
#include <stdint.h>

#define NN  100000
#define NME 400000
#define NWE 200000
// D = 128, 3D = 384

typedef __bf16 bf16;
typedef __bf16 bf16x8 __attribute__((ext_vector_type(8)));
typedef float  f32x4  __attribute__((ext_vector_type(4)));

static __device__ __forceinline__ bf16 f2bf(float f) {
    union { unsigned int i; float f; } v; v.f = f;
    unsigned int r = (v.i + 0x7fffu + ((v.i >> 16) & 1u)) >> 16;
    union { unsigned short s; bf16 b; } u; u.s = (unsigned short)r;
    return u.b;
}

// ---------------------------------------------------------------------------
// Weight prep: read fp32 W1 (384x128), W2, W3 (128x128); write transposed bf16
// so the MFMA B-fragment (8 consecutive k for fixed n) is a contiguous 16B load.
// ---------------------------------------------------------------------------
__global__ void prep_weights(const float* __restrict__ W1, const float* __restrict__ W2,
                             const float* __restrict__ W3, bf16* __restrict__ W1t,
                             bf16* __restrict__ W2t, bf16* __restrict__ W3t) {
    int tid = blockIdx.x * 256 + threadIdx.x;
    if (tid < 49152) {                    // W1: k in [0,384), n in [0,128)
        int k = tid >> 7, n = tid & 127;
        W1t[n * 384 + k] = f2bf(W1[tid]);
    } else if (tid < 65536) {
        int t2 = tid - 49152;
        int k = t2 >> 7, n = t2 & 127;
        W2t[n * 128 + k] = f2bf(W2[t2]);
    } else if (tid < 81920) {
        int t2 = tid - 65536;
        int k = t2 >> 7, n = t2 & 127;
        W3t[n * 128 + k] = f2bf(W3[t2]);
    }
}

// ---------------------------------------------------------------------------
// CSR build, step 1: per-receiver degree histogram (int atomics, tiny traffic).
// ---------------------------------------------------------------------------
__global__ __launch_bounds__(256) void count_edges(const int* __restrict__ mrecv,
                                                   const int* __restrict__ wrecv,
                                                   int* __restrict__ mdeg,
                                                   int* __restrict__ wdeg) {
    int t = blockIdx.x * 256 + threadIdx.x;
    if (t < NME) {
        atomicAdd(mdeg + mrecv[t], 1);
    } else {
        int t2 = t - NME;
        if (t2 < NWE) atomicAdd(wdeg + wrecv[t2], 1);
    }
}

// ---------------------------------------------------------------------------
// CSR build, step 2a: per-block partial sums. 25 blocks per segment, each
// covering a 4096-int window with coalesced int4 loads.
// ---------------------------------------------------------------------------
__global__ __launch_bounds__(256) void scan_part(const int* __restrict__ mdeg,
                                                 const int* __restrict__ wdeg,
                                                 int* __restrict__ bsum) {
    const int nblk = 25;                      // ceil(100000 / 4096)
    int seg = blockIdx.x / nblk;
    int blk = blockIdx.x % nblk;
    const int* deg = (seg == 0) ? mdeg : wdeg;
    const int t = threadIdx.x;
    const int base = blk * 4096;
    int sum = 0;
#pragma unroll
    for (int i = 0; i < 4; ++i) {
        int idx = base + (i * 256 + t) * 4;   // 16B-aligned; NN % 4 == 0
        if (idx < NN) {
            int4 v = *(const int4*)(deg + idx);
            sum += v.x + v.y + v.z + v.w;
        }
    }
#pragma unroll
    for (int m = 1; m < 64; m <<= 1) sum += __shfl_xor(sum, m, 64);
    __shared__ int ssum[4];
    if ((t & 63) == 0) ssum[t >> 6] = sum;
    __syncthreads();
    if (t == 0) bsum[blockIdx.x] = ssum[0] + ssum[1] + ssum[2] + ssum[3];
}

// ---------------------------------------------------------------------------
// CSR build, step 2b: block-local exclusive scan + block offset, writes
// off (in place over deg) and cur.
// ---------------------------------------------------------------------------
__global__ __launch_bounds__(256) void scan_write(int* __restrict__ mdeg, int* __restrict__ wdeg,
                                                  int* __restrict__ mcur, int* __restrict__ wcur,
                                                  const int* __restrict__ bsum) {
    __shared__ int sprefix;
    __shared__ int sscan[256];
    const int nblk = 25;
    int seg = blockIdx.x / nblk;
    int blk = blockIdx.x % nblk;
    int* deg = (seg == 0) ? mdeg : wdeg;
    int* cur = (seg == 0) ? mcur : wcur;
    const int t = threadIdx.x;
    if (t == 0) {
        int s = 0;
        const int* bs = bsum + seg * nblk;
        for (int i = 0; i < blk; ++i) s += bs[i];
        sprefix = s;
    }
    const int base = blk * 4096 + t * 16;
    int v[16];
#pragma unroll
    for (int i = 0; i < 16; i += 4) {
        int idx = base + i;                   // 16B-aligned; NN % 4 == 0
        if (idx < NN) {
            int4 q = *(const int4*)(deg + idx);
            v[i] = q.x; v[i + 1] = q.y; v[i + 2] = q.z; v[i + 3] = q.w;
        } else {
            v[i] = v[i + 1] = v[i + 2] = v[i + 3] = 0;
        }
    }
    int lsum = 0;
#pragma unroll
    for (int i = 0; i < 16; ++i) lsum += v[i];
    sscan[t] = lsum;
    __syncthreads();
    for (int d = 1; d < 256; d <<= 1) {       // inclusive scan of thread sums
        int vv = (t >= d) ? sscan[t - d] : 0;
        __syncthreads();
        sscan[t] += vv;
        __syncthreads();
    }
    int run = sprefix + sscan[t] - lsum;      // exclusive prefix for this thread
#pragma unroll
    for (int i = 0; i < 16; i += 4) {
        int idx = base + i;
        if (idx < NN) {
            int4 o;
            o.x = run; run += v[i];
            o.y = run; run += v[i + 1];
            o.z = run; run += v[i + 2];
            o.w = run; run += v[i + 3];
            *(int4*)(deg + idx) = o;
            *(int4*)(cur + idx) = o;
        }
    }
}

// ---------------------------------------------------------------------------
// CSR build, step 3: bucket edge ids by receiver (cursor atomics).
// ---------------------------------------------------------------------------
__global__ __launch_bounds__(256) void fill_lists(const int* __restrict__ mrecv,
                                                  const int* __restrict__ wrecv,
                                                  int* __restrict__ mcur, int* __restrict__ wcur,
                                                  int* __restrict__ mlist, int* __restrict__ wlist) {
    int t = blockIdx.x * 256 + threadIdx.x;
    if (t < NME) {
        int r = mrecv[t];
        int p = atomicAdd(mcur + r, 1);
        mlist[p] = t;
    } else {
        int t2 = t - NME;
        if (t2 < NWE) {
            int r = wrecv[t2];
            int p = atomicAdd(wcur + r, 1);
            wlist[p] = t2;
        }
    }
}

// ---------------------------------------------------------------------------
// Gather: quarter-wave (16 lanes) per node; lane g sums floats [g*8, g*8+8)
// across the node's incoming edges (fp32 accum), writes bf16 agg row once.
// ---------------------------------------------------------------------------
__global__ __launch_bounds__(256) void gather_sum(const float* __restrict__ attr,
                                                  const int* __restrict__ off,
                                                  const int* __restrict__ list,
                                                  bf16* __restrict__ agg, int nE) {
    int t = blockIdx.x * 256 + threadIdx.x;
    int node = t >> 4;
    int g = t & 15;
    if (node >= NN) return;
    int j0 = off[node];
    int j1 = (node == NN - 1) ? nE : off[node + 1];
    f32x4 lo = (f32x4)0.0f, hi = (f32x4)0.0f;
    for (int j = j0; j < j1; ++j) {
        int e = list[j];
        const float* src = attr + (size_t)e * 128 + g * 8;
        f32x4 a = *(const f32x4*)(src);
        f32x4 b = *(const f32x4*)(src + 4);
        lo += a;
        hi += b;
    }
    bf16x8 o;
#pragma unroll
    for (int i = 0; i < 4; ++i) {
        o[i]     = f2bf(lo[i]);
        o[4 + i] = f2bf(hi[i]);
    }
    *(bf16x8*)(agg + (size_t)node * 128 + g * 8) = o;
}

// ---------------------------------------------------------------------------
// Fused node MLP + LayerNorm, M=32 per wave, TWO WAVES PER BLOCK.
// 128-thread blocks -> grid 1563 (~6 blocks/CU, ~12 waves/CU) vs R2's 782
// 4-wave blocks (3 blocks/CU): more independent waves to hide the L2
// weight-load latency this kernel is bound by.
// Two 16-row A-fragments share every B-fragment (2 MFMA per 16B weight load).
// Layer1: K=384 over [x (fp32->bf16) | mesh_agg (bf16) | world_agg (bf16)];
// Layers 2/3: K=128 with LDS round-trip (C-layout -> A-layout).
// LayerNorm via 16-lane xor-shuffles. fp32 output.
// ---------------------------------------------------------------------------
__global__ __launch_bounds__(128) void node_mlp(
    const float* __restrict__ x, const bf16* __restrict__ magg,
    const bf16* __restrict__ wagg, const bf16* __restrict__ W1t,
    const bf16* __restrict__ W2t, const bf16* __restrict__ W3t,
    const float* __restrict__ b1, const float* __restrict__ b2,
    const float* __restrict__ b3, const float* __restrict__ gam,
    const float* __restrict__ bet, float* __restrict__ out) {
    __shared__ bf16 sh[2 * 32 * 136];  // per-wave 32x(128+8) bf16 tile
    const int wave = threadIdx.x >> 6;
    const int lane = threadIdx.x & 63;
    const int quad = lane >> 4;
    const int l16 = lane & 15;
    const int node_base = blockIdx.x * 64 + wave * 32;
    bf16* shw = sh + wave * (32 * 136);

    int arow[2];
    arow[0] = node_base + l16;
    arow[1] = node_base + 16 + l16;
    if (arow[0] >= NN) arow[0] = NN - 1;  // clamp; stores are guarded
    if (arow[1] >= NN) arow[1] = NN - 1;

    // ---- Layer 1: [32 x 384] @ [384 x 128] ----
    f32x4 acc[2][8];
#pragma unroll
    for (int rg = 0; rg < 2; ++rg)
#pragma unroll
        for (int t = 0; t < 8; ++t) acc[rg][t] = (f32x4)0.0f;

#pragma unroll
    for (int ks = 0; ks < 12; ++ks) {
        int kg = ks * 32 + quad * 8;  // this lane's k-base in [0,384)
        bf16x8 af[2];
#pragma unroll
        for (int rg = 0; rg < 2; ++rg) {
            if (ks < 4) {
                const float* src = x + (size_t)arow[rg] * 128 + kg;
                f32x4 lo = *(const f32x4*)(src);
                f32x4 hi = *(const f32x4*)(src + 4);
#pragma unroll
                for (int i = 0; i < 4; ++i) {
                    af[rg][i]     = f2bf(lo[i]);
                    af[rg][4 + i] = f2bf(hi[i]);
                }
            } else if (ks < 8) {
                af[rg] = *(const bf16x8*)(magg + (size_t)arow[rg] * 128 + (kg - 128));
            } else {
                af[rg] = *(const bf16x8*)(wagg + (size_t)arow[rg] * 128 + (kg - 256));
            }
        }
#pragma unroll
        for (int t = 0; t < 8; ++t) {
            bf16x8 bfrag = *(const bf16x8*)(W1t + (t * 16 + l16) * 384 + ks * 32 + quad * 8);
            acc[0][t] = __builtin_amdgcn_mfma_f32_16x16x32_bf16(af[0], bfrag, acc[0][t], 0, 0, 0);
            acc[1][t] = __builtin_amdgcn_mfma_f32_16x16x32_bf16(af[1], bfrag, acc[1][t], 0, 0, 0);
        }
    }
    // bias + relu, C-layout -> LDS (bf16)
#pragma unroll
    for (int t = 0; t < 8; ++t) {
        float bv = b1[t * 16 + l16];
#pragma unroll
        for (int rg = 0; rg < 2; ++rg)
#pragma unroll
            for (int r = 0; r < 4; ++r) {
                float h = acc[rg][t][r] + bv;
                h = h > 0.0f ? h : 0.0f;
                shw[(rg * 16 + quad * 4 + r) * 136 + t * 16 + l16] = f2bf(h);
            }
    }
    __syncthreads();

    // ---- Layer 2: [32 x 128] @ [128 x 128] ----
    bf16x8 a2[2][4];
#pragma unroll
    for (int rg = 0; rg < 2; ++rg)
#pragma unroll
        for (int ks = 0; ks < 4; ++ks)
            a2[rg][ks] = *(const bf16x8*)(shw + (rg * 16 + l16) * 136 + ks * 32 + quad * 8);
#pragma unroll
    for (int rg = 0; rg < 2; ++rg)
#pragma unroll
        for (int t = 0; t < 8; ++t) acc[rg][t] = (f32x4)0.0f;
#pragma unroll
    for (int ks = 0; ks < 4; ++ks) {
#pragma unroll
        for (int t = 0; t < 8; ++t) {
            bf16x8 bfrag = *(const bf16x8*)(W2t + (t * 16 + l16) * 128 + ks * 32 + quad * 8);
            acc[0][t] = __builtin_amdgcn_mfma_f32_16x16x32_bf16(a2[0][ks], bfrag, acc[0][t], 0, 0, 0);
            acc[1][t] = __builtin_amdgcn_mfma_f32_16x16x32_bf16(a2[1][ks], bfrag, acc[1][t], 0, 0, 0);
        }
    }
    __syncthreads();
#pragma unroll
    for (int t = 0; t < 8; ++t) {
        float bv = b2[t * 16 + l16];
#pragma unroll
        for (int rg = 0; rg < 2; ++rg)
#pragma unroll
            for (int r = 0; r < 4; ++r) {
                float h = acc[rg][t][r] + bv;
                h = h > 0.0f ? h : 0.0f;
                shw[(rg * 16 + quad * 4 + r) * 136 + t * 16 + l16] = f2bf(h);
            }
    }
    __syncthreads();

    // ---- Layer 3: [32 x 128] @ [128 x 128] (no relu) ----
#pragma unroll
    for (int rg = 0; rg < 2; ++rg)
#pragma unroll
        for (int ks = 0; ks < 4; ++ks)
            a2[rg][ks] = *(const bf16x8*)(shw + (rg * 16 + l16) * 136 + ks * 32 + quad * 8);
#pragma unroll
    for (int rg = 0; rg < 2; ++rg)
#pragma unroll
        for (int t = 0; t < 8; ++t) acc[rg][t] = (f32x4)0.0f;
#pragma unroll
    for (int ks = 0; ks < 4; ++ks) {
#pragma unroll
        for (int t = 0; t < 8; ++t) {
            bf16x8 bfrag = *(const bf16x8*)(W3t + (t * 16 + l16) * 128 + ks * 32 + quad * 8);
            acc[0][t] = __builtin_amdgcn_mfma_f32_16x16x32_bf16(a2[0][ks], bfrag, acc[0][t], 0, 0, 0);
            acc[1][t] = __builtin_amdgcn_mfma_f32_16x16x32_bf16(a2[1][ks], bfrag, acc[1][t], 0, 0, 0);
        }
    }
    // add b3
#pragma unroll
    for (int t = 0; t < 8; ++t) {
        float bv = b3[t * 16 + l16];
#pragma unroll
        for (int rg = 0; rg < 2; ++rg)
#pragma unroll
            for (int r = 0; r < 4; ++r) acc[rg][t][r] += bv;
    }

    // ---- LayerNorm over the 128 cols of each row ----
    float gv[8], bv2[8];
#pragma unroll
    for (int t = 0; t < 8; ++t) {
        gv[t]  = gam[t * 16 + l16];
        bv2[t] = bet[t * 16 + l16];
    }
#pragma unroll
    for (int rg = 0; rg < 2; ++rg) {
        float mean[4], rstd[4];
#pragma unroll
        for (int r = 0; r < 4; ++r) {
            float s = 0.0f, s2 = 0.0f;
#pragma unroll
            for (int t = 0; t < 8; ++t) {
                float v = acc[rg][t][r];
                s += v;
                s2 += v * v;
            }
#pragma unroll
            for (int m = 1; m < 16; m <<= 1) {
                s  += __shfl_xor(s, m, 64);
                s2 += __shfl_xor(s2, m, 64);
            }
            float mu = s * (1.0f / 128.0f);
            float var = s2 * (1.0f / 128.0f) - mu * mu;
            mean[r] = mu;
            rstd[r] = rsqrtf(var + 1e-5f);
        }
#pragma unroll
        for (int r = 0; r < 4; ++r) {
            int row = node_base + rg * 16 + quad * 4 + r;
            if (row < NN) {
#pragma unroll
                for (int t = 0; t < 8; ++t) {
                    float o = (acc[rg][t][r] - mean[r]) * rstd[r] * gv[t] + bv2[t];
                    out[(size_t)row * 128 + t * 16 + l16] = o;
                }
            }
        }
    }
}

// ---------------------------------------------------------------------------
extern "C" void kernel_launch(void* const* d_in, const int* in_sizes, int n_in,
                              void* d_out, int out_size, void* d_ws, size_t ws_size,
                              hipStream_t stream) {
    const float* x   = (const float*)d_in[0];
    const float* ea  = (const float*)d_in[1];
    const int*   ei  = (const int*)d_in[2];   // (2, NME) flat; recv row at offset NME
    const float* wea = (const float*)d_in[3];
    const int*   wei = (const int*)d_in[4];   // (2, NWE) flat; recv row at offset NWE
    const float* W1  = (const float*)d_in[5];
    const float* b1  = (const float*)d_in[6];
    const float* W2  = (const float*)d_in[7];
    const float* b2  = (const float*)d_in[8];
    const float* W3  = (const float*)d_in[9];
    const float* b3  = (const float*)d_in[10];
    const float* gam = (const float*)d_in[11];
    const float* bet = (const float*)d_in[12];

    char* ws = (char*)d_ws;
    bf16* magg = (bf16*)(ws);                      // 25,600,000 B
    bf16* wagg = (bf16*)(ws + 25600000);           // 25,600,000 B
    bf16* W1t  = (bf16*)(ws + 51200000);           // 98,304 B
    bf16* W2t  = (bf16*)(ws + 51298304);           // 32,768 B
    bf16* W3t  = (bf16*)(ws + 51331072);           // 32,768 B
    int*  mdeg = (int*)(ws + 51363840);            // 400,000 B (deg -> off in place)
    int*  wdeg = (int*)(ws + 51763840);            // 400,000 B (contiguous with mdeg)
    int*  mcur = (int*)(ws + 52163840);            // 400,000 B
    int*  wcur = (int*)(ws + 52563840);            // 400,000 B
    int*  mlist = (int*)(ws + 52963840);           // 1,600,000 B
    int*  wlist = (int*)(ws + 54563840);           // 800,000 B
    int*  bsum  = (int*)(ws + 55363840);           // 200 B (50 block partial sums)

    // zero only the two degree arrays (contiguous 800 KB)
    hipMemsetAsync(ws + 51363840, 0, 800000, stream);

    prep_weights<<<320, 256, 0, stream>>>(W1, W2, W3, W1t, W2t, W3t);

    count_edges<<<(NME + NWE + 255) / 256, 256, 0, stream>>>(ei + NME, wei + NWE, mdeg, wdeg);
    scan_part<<<50, 256, 0, stream>>>(mdeg, wdeg, bsum);
    scan_write<<<50, 256, 0, stream>>>(mdeg, wdeg, mcur, wcur, bsum);
    fill_lists<<<(NME + NWE + 255) / 256, 256, 0, stream>>>(ei + NME, wei + NWE,
                                                            mcur, wcur, mlist, wlist);

    gather_sum<<<(NN * 16 + 255) / 256, 256, 0, stream>>>(ea, mdeg, mlist, magg, NME);
    gather_sum<<<(NN * 16 + 255) / 256, 256, 0, stream>>>(wea, wdeg, wlist, wagg, NWE);

    node_mlp<<<(NN + 63) / 64, 128, 0, stream>>>(x, magg, wagg, W1t, W2t, W3t,
                                                 b1, b2, b3, gam, bet, (float*)d_out);
}

// Round 6
// 539.019 us; speedup vs baseline: 1.5682x; 1.0585x over previous
//
#include <hip/hip_runtime.h>
#include <hip/hip_bf16.h>
#include <stdint.h>

#define NN  100000
#define NME 400000
#define NWE 200000
// D = 128, 3D = 384

typedef __bf16 bf16;
typedef __bf16 bf16x8 __attribute__((ext_vector_type(8)));
typedef float  f32x4  __attribute__((ext_vector_type(4)));

static __device__ __forceinline__ bf16 f2bf(float f) {
    union { unsigned int i; float f; } v; v.f = f;
    unsigned int r = (v.i + 0x7fffu + ((v.i >> 16) & 1u)) >> 16;
    union { unsigned short s; bf16 b; } u; u.s = (unsigned short)r;
    return u.b;
}

// ---------------------------------------------------------------------------
// Weight prep: read fp32 W1 (384x128), W2, W3 (128x128); write transposed bf16
// so the MFMA B-fragment (8 consecutive k for fixed n) is a contiguous 16B load.
// ---------------------------------------------------------------------------
__global__ void prep_weights(const float* __restrict__ W1, const float* __restrict__ W2,
                             const float* __restrict__ W3, bf16* __restrict__ W1t,
                             bf16* __restrict__ W2t, bf16* __restrict__ W3t) {
    int tid = blockIdx.x * 256 + threadIdx.x;
    if (tid < 49152) {                    // W1: k in [0,384), n in [0,128)
        int k = tid >> 7, n = tid & 127;
        W1t[n * 384 + k] = f2bf(W1[tid]);
    } else if (tid < 65536) {
        int t2 = tid - 49152;
        int k = t2 >> 7, n = t2 & 127;
        W2t[n * 128 + k] = f2bf(W2[t2]);
    } else if (tid < 81920) {
        int t2 = tid - 65536;
        int k = t2 >> 7, n = t2 & 127;
        W3t[n * 128 + k] = f2bf(W3[t2]);
    }
}

// ---------------------------------------------------------------------------
// CSR build, step 1: per-receiver degree histogram (int atomics, tiny traffic).
// ---------------------------------------------------------------------------
__global__ __launch_bounds__(256) void count_edges(const int* __restrict__ mrecv,
                                                   const int* __restrict__ wrecv,
                                                   int* __restrict__ mdeg,
                                                   int* __restrict__ wdeg) {
    int t = blockIdx.x * 256 + threadIdx.x;
    if (t < NME) {
        atomicAdd(mdeg + mrecv[t], 1);
    } else {
        int t2 = t - NME;
        if (t2 < NWE) atomicAdd(wdeg + wrecv[t2], 1);
    }
}

// ---------------------------------------------------------------------------
// CSR build, step 2a: per-block partial sums. 25 blocks per segment, each
// covering a 4096-int window with coalesced int4 loads.
// ---------------------------------------------------------------------------
__global__ __launch_bounds__(256) void scan_part(const int* __restrict__ mdeg,
                                                 const int* __restrict__ wdeg,
                                                 int* __restrict__ bsum) {
    const int nblk = 25;                      // ceil(100000 / 4096)
    int seg = blockIdx.x / nblk;
    int blk = blockIdx.x % nblk;
    const int* deg = (seg == 0) ? mdeg : wdeg;
    const int t = threadIdx.x;
    const int base = blk * 4096;
    int sum = 0;
#pragma unroll
    for (int i = 0; i < 4; ++i) {
        int idx = base + (i * 256 + t) * 4;   // 16B-aligned; NN % 4 == 0
        if (idx < NN) {
            int4 v = *(const int4*)(deg + idx);
            sum += v.x + v.y + v.z + v.w;
        }
    }
#pragma unroll
    for (int m = 1; m < 64; m <<= 1) sum += __shfl_xor(sum, m, 64);
    __shared__ int ssum[4];
    if ((t & 63) == 0) ssum[t >> 6] = sum;
    __syncthreads();
    if (t == 0) bsum[blockIdx.x] = ssum[0] + ssum[1] + ssum[2] + ssum[3];
}

// ---------------------------------------------------------------------------
// CSR build, step 2b: block-local exclusive scan + block offset, writes
// off (in place over deg) and cur.
// ---------------------------------------------------------------------------
__global__ __launch_bounds__(256) void scan_write(int* __restrict__ mdeg, int* __restrict__ wdeg,
                                                  int* __restrict__ mcur, int* __restrict__ wcur,
                                                  const int* __restrict__ bsum) {
    __shared__ int sprefix;
    __shared__ int sscan[256];
    const int nblk = 25;
    int seg = blockIdx.x / nblk;
    int blk = blockIdx.x % nblk;
    int* deg = (seg == 0) ? mdeg : wdeg;
    int* cur = (seg == 0) ? mcur : wcur;
    const int t = threadIdx.x;
    if (t == 0) {
        int s = 0;
        const int* bs = bsum + seg * nblk;
        for (int i = 0; i < blk; ++i) s += bs[i];
        sprefix = s;
    }
    const int base = blk * 4096 + t * 16;
    int v[16];
#pragma unroll
    for (int i = 0; i < 16; i += 4) {
        int idx = base + i;                   // 16B-aligned; NN % 4 == 0
        if (idx < NN) {
            int4 q = *(const int4*)(deg + idx);
            v[i] = q.x; v[i + 1] = q.y; v[i + 2] = q.z; v[i + 3] = q.w;
        } else {
            v[i] = v[i + 1] = v[i + 2] = v[i + 3] = 0;
        }
    }
    int lsum = 0;
#pragma unroll
    for (int i = 0; i < 16; ++i) lsum += v[i];
    sscan[t] = lsum;
    __syncthreads();
    for (int d = 1; d < 256; d <<= 1) {       // inclusive scan of thread sums
        int vv = (t >= d) ? sscan[t - d] : 0;
        __syncthreads();
        sscan[t] += vv;
        __syncthreads();
    }
    int run = sprefix + sscan[t] - lsum;      // exclusive prefix for this thread
#pragma unroll
    for (int i = 0; i < 16; i += 4) {
        int idx = base + i;
        if (idx < NN) {
            int4 o;
            o.x = run; run += v[i];
            o.y = run; run += v[i + 1];
            o.z = run; run += v[i + 2];
            o.w = run; run += v[i + 3];
            *(int4*)(deg + idx) = o;
            *(int4*)(cur + idx) = o;
        }
    }
}

// ---------------------------------------------------------------------------
// CSR build, step 3: bucket edge ids by receiver (cursor atomics).
// ---------------------------------------------------------------------------
__global__ __launch_bounds__(256) void fill_lists(const int* __restrict__ mrecv,
                                                  const int* __restrict__ wrecv,
                                                  int* __restrict__ mcur, int* __restrict__ wcur,
                                                  int* __restrict__ mlist, int* __restrict__ wlist) {
    int t = blockIdx.x * 256 + threadIdx.x;
    if (t < NME) {
        int r = mrecv[t];
        int p = atomicAdd(mcur + r, 1);
        mlist[p] = t;
    } else {
        int t2 = t - NME;
        if (t2 < NWE) {
            int r = wrecv[t2];
            int p = atomicAdd(wcur + r, 1);
            wlist[p] = t2;
        }
    }
}

// ---------------------------------------------------------------------------
// Gather: quarter-wave (16 lanes) per node; lane g sums floats [g*8, g*8+8)
// across the node's incoming edges (fp32 accum), writes bf16 agg row once.
// ---------------------------------------------------------------------------
__global__ __launch_bounds__(256) void gather_sum(const float* __restrict__ attr,
                                                  const int* __restrict__ off,
                                                  const int* __restrict__ list,
                                                  bf16* __restrict__ agg, int nE) {
    int t = blockIdx.x * 256 + threadIdx.x;
    int node = t >> 4;
    int g = t & 15;
    if (node >= NN) return;
    int j0 = off[node];
    int j1 = (node == NN - 1) ? nE : off[node + 1];
    f32x4 lo = (f32x4)0.0f, hi = (f32x4)0.0f;
    for (int j = j0; j < j1; ++j) {
        int e = list[j];
        const float* src = attr + (size_t)e * 128 + g * 8;
        f32x4 a = *(const f32x4*)(src);
        f32x4 b = *(const f32x4*)(src + 4);
        lo += a;
        hi += b;
    }
    bf16x8 o;
#pragma unroll
    for (int i = 0; i < 4; ++i) {
        o[i]     = f2bf(lo[i]);
        o[4 + i] = f2bf(hi[i]);
    }
    *(bf16x8*)(agg + (size_t)node * 128 + g * 8) = o;
}

// ---------------------------------------------------------------------------
// Weight-slice source address for cooperative LDS staging.
// Slices 0..11 = W1t k-slices, 12..15 = W2t, 16..19 = W3t (32 k each, 8 KB).
// Slot s (0..511): tile = s>>6, q = (s>>4)&3, l16 = s&15, n = tile*16+l16.
// LDS layout is lane-dense: slot s at byte s*16, so a wave's B-frag read for
// col-tile t covers bytes [t*1024, t*1024+1024) -> conflict-free ds_read_b128.
// ---------------------------------------------------------------------------
static __device__ __forceinline__ const int4* wsrc(const bf16* __restrict__ W1t,
                                                   const bf16* __restrict__ W2t,
                                                   const bf16* __restrict__ W3t,
                                                   int slice, int n, int q) {
    const bf16* W; int ld, kb;
    if (slice < 12)      { W = W1t; ld = 384; kb = slice * 32; }
    else if (slice < 16) { W = W2t; ld = 128; kb = (slice - 12) * 32; }
    else                 { W = W3t; ld = 128; kb = (slice - 16) * 32; }
    return (const int4*)(W + n * ld + kb + q * 8);
}

// ---------------------------------------------------------------------------
// Fused node MLP + LayerNorm with cooperative double-buffered LDS weight
// staging. 256 threads = 4 waves, M=32/wave -> 128 nodes/block, 782 blocks.
// R5 diagnosis: avg wave lifetime ~54 us vs ~2.5 us of work -> each wave was
// a chain of ~190 serial L2 round-trips for its private weight loads. Now
// each 8 KB weight slice is loaded from L2 once per BLOCK (4 waves share),
// reg-staged at phase top (latency hidden under 16 MFMAs) and ds_written
// after the barrier (2-barrier double-buffer). B-frag values and MFMA order
// are byte-identical to R5 -> same numerics.
// ---------------------------------------------------------------------------
__global__ __launch_bounds__(256) void node_mlp(
    const float* __restrict__ x, const bf16* __restrict__ magg,
    const bf16* __restrict__ wagg, const bf16* __restrict__ W1t,
    const bf16* __restrict__ W2t, const bf16* __restrict__ W3t,
    const float* __restrict__ b1, const float* __restrict__ b2,
    const float* __restrict__ b3, const float* __restrict__ gam,
    const float* __restrict__ bet, float* __restrict__ out) {
    __shared__ bf16 sh_w[2][4096];      // double-buffered 8 KB weight slice
    __shared__ bf16 sh_h[4][32 * 136];  // per-wave h tile (row stride 272 B)
    const int tid  = threadIdx.x;
    const int wave = tid >> 6;
    const int lane = tid & 63;
    const int quad = lane >> 4;
    const int l16  = lane & 15;
    const int node_base = blockIdx.x * 128 + wave * 32;
    bf16* shw = sh_h[wave];

    // staging slots: this thread owns slots tid and tid+256
    const int s0 = tid, s1 = tid + 256;
    const int n0 = ((s0 >> 6) << 4) | (s0 & 15), q0 = (s0 >> 4) & 3;
    const int n1 = ((s1 >> 6) << 4) | (s1 & 15), q1 = (s1 >> 4) & 3;
    int4 st0, st1;

    // prologue: stage slice 0 into buf 0
    st0 = *wsrc(W1t, W2t, W3t, 0, n0, q0);
    st1 = *wsrc(W1t, W2t, W3t, 0, n1, q1);
    *(int4*)(&sh_w[0][s0 * 8]) = st0;
    *(int4*)(&sh_w[0][s1 * 8]) = st1;
    __syncthreads();

    int arow[2];
    arow[0] = node_base + l16;
    arow[1] = node_base + 16 + l16;
    if (arow[0] >= NN) arow[0] = NN - 1;  // clamp; stores are guarded
    if (arow[1] >= NN) arow[1] = NN - 1;

    f32x4 acc[2][8];
#pragma unroll
    for (int rg = 0; rg < 2; ++rg)
#pragma unroll
        for (int t = 0; t < 8; ++t) acc[rg][t] = (f32x4)0.0f;

    // ---- Layer 1: [32 x 384] @ [384 x 128], slices 0..11 ----
#pragma unroll
    for (int ks = 0; ks < 12; ++ks) {
        // issue next-slice loads early (latency hides under MFMAs)
        st0 = *wsrc(W1t, W2t, W3t, ks + 1, n0, q0);
        st1 = *wsrc(W1t, W2t, W3t, ks + 1, n1, q1);
        // A fragments for this k-slice
        int kg = ks * 32 + quad * 8;
        bf16x8 af[2];
#pragma unroll
        for (int rg = 0; rg < 2; ++rg) {
            if (ks < 4) {
                const float* src = x + (size_t)arow[rg] * 128 + kg;
                f32x4 lo = *(const f32x4*)(src);
                f32x4 hi = *(const f32x4*)(src + 4);
#pragma unroll
                for (int i = 0; i < 4; ++i) {
                    af[rg][i]     = f2bf(lo[i]);
                    af[rg][4 + i] = f2bf(hi[i]);
                }
            } else if (ks < 8) {
                af[rg] = *(const bf16x8*)(magg + (size_t)arow[rg] * 128 + (kg - 128));
            } else {
                af[rg] = *(const bf16x8*)(wagg + (size_t)arow[rg] * 128 + (kg - 256));
            }
        }
        const bf16* wb = sh_w[ks & 1];
#pragma unroll
        for (int t = 0; t < 8; ++t) {
            bf16x8 bfrag = *(const bf16x8*)(wb + t * 512 + lane * 8);
            acc[0][t] = __builtin_amdgcn_mfma_f32_16x16x32_bf16(af[0], bfrag, acc[0][t], 0, 0, 0);
            acc[1][t] = __builtin_amdgcn_mfma_f32_16x16x32_bf16(af[1], bfrag, acc[1][t], 0, 0, 0);
        }
        __syncthreads();
        *(int4*)(&sh_w[(ks + 1) & 1][s0 * 8]) = st0;
        *(int4*)(&sh_w[(ks + 1) & 1][s1 * 8]) = st1;
        __syncthreads();
    }
    // bias + relu, C-layout -> h tile (wave-local LDS, no barrier needed)
#pragma unroll
    for (int t = 0; t < 8; ++t) {
        float bv = b1[t * 16 + l16];
#pragma unroll
        for (int rg = 0; rg < 2; ++rg)
#pragma unroll
            for (int r = 0; r < 4; ++r) {
                float h = acc[rg][t][r] + bv;
                h = h > 0.0f ? h : 0.0f;
                shw[(rg * 16 + quad * 4 + r) * 136 + t * 16 + l16] = f2bf(h);
            }
    }

    // ---- Layer 2: [32 x 128] @ [128 x 128], slices 12..15 ----
#pragma unroll
    for (int rg = 0; rg < 2; ++rg)
#pragma unroll
        for (int t = 0; t < 8; ++t) acc[rg][t] = (f32x4)0.0f;
#pragma unroll
    for (int ks = 0; ks < 4; ++ks) {
        st0 = *wsrc(W1t, W2t, W3t, 13 + ks, n0, q0);
        st1 = *wsrc(W1t, W2t, W3t, 13 + ks, n1, q1);
        bf16x8 a2[2];
        a2[0] = *(const bf16x8*)(shw + l16 * 136 + ks * 32 + quad * 8);
        a2[1] = *(const bf16x8*)(shw + (16 + l16) * 136 + ks * 32 + quad * 8);
        const bf16* wb = sh_w[ks & 1];   // slice 12+ks lives in buf (12+ks)&1 = ks&1
#pragma unroll
        for (int t = 0; t < 8; ++t) {
            bf16x8 bfrag = *(const bf16x8*)(wb + t * 512 + lane * 8);
            acc[0][t] = __builtin_amdgcn_mfma_f32_16x16x32_bf16(a2[0], bfrag, acc[0][t], 0, 0, 0);
            acc[1][t] = __builtin_amdgcn_mfma_f32_16x16x32_bf16(a2[1], bfrag, acc[1][t], 0, 0, 0);
        }
        __syncthreads();
        *(int4*)(&sh_w[(13 + ks) & 1][s0 * 8]) = st0;
        *(int4*)(&sh_w[(13 + ks) & 1][s1 * 8]) = st1;
        __syncthreads();
    }
#pragma unroll
    for (int t = 0; t < 8; ++t) {
        float bv = b2[t * 16 + l16];
#pragma unroll
        for (int rg = 0; rg < 2; ++rg)
#pragma unroll
            for (int r = 0; r < 4; ++r) {
                float h = acc[rg][t][r] + bv;
                h = h > 0.0f ? h : 0.0f;
                shw[(rg * 16 + quad * 4 + r) * 136 + t * 16 + l16] = f2bf(h);
            }
    }

    // ---- Layer 3: [32 x 128] @ [128 x 128], slices 16..19 (no relu) ----
#pragma unroll
    for (int rg = 0; rg < 2; ++rg)
#pragma unroll
        for (int t = 0; t < 8; ++t) acc[rg][t] = (f32x4)0.0f;
#pragma unroll
    for (int ks = 0; ks < 4; ++ks) {
        if (ks < 3) {
            st0 = *wsrc(W1t, W2t, W3t, 17 + ks, n0, q0);
            st1 = *wsrc(W1t, W2t, W3t, 17 + ks, n1, q1);
        }
        bf16x8 a2[2];
        a2[0] = *(const bf16x8*)(shw + l16 * 136 + ks * 32 + quad * 8);
        a2[1] = *(const bf16x8*)(shw + (16 + l16) * 136 + ks * 32 + quad * 8);
        const bf16* wb = sh_w[ks & 1];   // slice 16+ks in buf (16+ks)&1 = ks&1
#pragma unroll
        for (int t = 0; t < 8; ++t) {
            bf16x8 bfrag = *(const bf16x8*)(wb + t * 512 + lane * 8);
            acc[0][t] = __builtin_amdgcn_mfma_f32_16x16x32_bf16(a2[0], bfrag, acc[0][t], 0, 0, 0);
            acc[1][t] = __builtin_amdgcn_mfma_f32_16x16x32_bf16(a2[1], bfrag, acc[1][t], 0, 0, 0);
        }
        if (ks < 3) {
            __syncthreads();
            *(int4*)(&sh_w[(17 + ks) & 1][s0 * 8]) = st0;
            *(int4*)(&sh_w[(17 + ks) & 1][s1 * 8]) = st1;
            __syncthreads();
        }
    }
    // add b3
#pragma unroll
    for (int t = 0; t < 8; ++t) {
        float bv = b3[t * 16 + l16];
#pragma unroll
        for (int rg = 0; rg < 2; ++rg)
#pragma unroll
            for (int r = 0; r < 4; ++r) acc[rg][t][r] += bv;
    }

    // ---- LayerNorm over the 128 cols of each row ----
    float gv[8], bv2[8];
#pragma unroll
    for (int t = 0; t < 8; ++t) {
        gv[t]  = gam[t * 16 + l16];
        bv2[t] = bet[t * 16 + l16];
    }
#pragma unroll
    for (int rg = 0; rg < 2; ++rg) {
        float mean[4], rstd[4];
#pragma unroll
        for (int r = 0; r < 4; ++r) {
            float s = 0.0f, s2 = 0.0f;
#pragma unroll
            for (int t = 0; t < 8; ++t) {
                float v = acc[rg][t][r];
                s += v;
                s2 += v * v;
            }
#pragma unroll
            for (int m = 1; m < 16; m <<= 1) {
                s  += __shfl_xor(s, m, 64);
                s2 += __shfl_xor(s2, m, 64);
            }
            float mu = s * (1.0f / 128.0f);
            float var = s2 * (1.0f / 128.0f) - mu * mu;
            mean[r] = mu;
            rstd[r] = rsqrtf(var + 1e-5f);
        }
#pragma unroll
        for (int r = 0; r < 4; ++r) {
            int row = node_base + rg * 16 + quad * 4 + r;
            if (row < NN) {
#pragma unroll
                for (int t = 0; t < 8; ++t) {
                    float o = (acc[rg][t][r] - mean[r]) * rstd[r] * gv[t] + bv2[t];
                    out[(size_t)row * 128 + t * 16 + l16] = o;
                }
            }
        }
    }
}

// ---------------------------------------------------------------------------
extern "C" void kernel_launch(void* const* d_in, const int* in_sizes, int n_in,
                              void* d_out, int out_size, void* d_ws, size_t ws_size,
                              hipStream_t stream) {
    const float* x   = (const float*)d_in[0];
    const float* ea  = (const float*)d_in[1];
    const int*   ei  = (const int*)d_in[2];   // (2, NME) flat; recv row at offset NME
    const float* wea = (const float*)d_in[3];
    const int*   wei = (const int*)d_in[4];   // (2, NWE) flat; recv row at offset NWE
    const float* W1  = (const float*)d_in[5];
    const float* b1  = (const float*)d_in[6];
    const float* W2  = (const float*)d_in[7];
    const float* b2  = (const float*)d_in[8];
    const float* W3  = (const float*)d_in[9];
    const float* b3  = (const float*)d_in[10];
    const float* gam = (const float*)d_in[11];
    const float* bet = (const float*)d_in[12];

    char* ws = (char*)d_ws;
    bf16* magg = (bf16*)(ws);                      // 25,600,000 B
    bf16* wagg = (bf16*)(ws + 25600000);           // 25,600,000 B
    bf16* W1t  = (bf16*)(ws + 51200000);           // 98,304 B
    bf16* W2t  = (bf16*)(ws + 51298304);           // 32,768 B
    bf16* W3t  = (bf16*)(ws + 51331072);           // 32,768 B
    int*  mdeg = (int*)(ws + 51363840);            // 400,000 B (deg -> off in place)
    int*  wdeg = (int*)(ws + 51763840);            // 400,000 B (contiguous with mdeg)
    int*  mcur = (int*)(ws + 52163840);            // 400,000 B
    int*  wcur = (int*)(ws + 52563840);            // 400,000 B
    int*  mlist = (int*)(ws + 52963840);           // 1,600,000 B
    int*  wlist = (int*)(ws + 54563840);           // 800,000 B
    int*  bsum  = (int*)(ws + 55363840);           // 200 B (50 block partial sums)

    // zero only the two degree arrays (contiguous 800 KB)
    hipMemsetAsync(ws + 51363840, 0, 800000, stream);

    prep_weights<<<320, 256, 0, stream>>>(W1, W2, W3, W1t, W2t, W3t);

    count_edges<<<(NME + NWE + 255) / 256, 256, 0, stream>>>(ei + NME, wei + NWE, mdeg, wdeg);
    scan_part<<<50, 256, 0, stream>>>(mdeg, wdeg, bsum);
    scan_write<<<50, 256, 0, stream>>>(mdeg, wdeg, mcur, wcur, bsum);
    fill_lists<<<(NME + NWE + 255) / 256, 256, 0, stream>>>(ei + NME, wei + NWE,
                                                            mcur, wcur, mlist, wlist);

    gather_sum<<<(NN * 16 + 255) / 256, 256, 0, stream>>>(ea, mdeg, mlist, magg, NME);
    gather_sum<<<(NN * 16 + 255) / 256, 256, 0, stream>>>(wea, wdeg, wlist, wagg, NWE);

    node_mlp<<<(NN + 127) / 128, 256, 0, stream>>>(x, magg, wagg, W1t, W2t, W3t,
                                                   b1, b2, b3, gam, bet, (float*)d_out);
}

// Round 7
// 530.965 us; speedup vs baseline: 1.5920x; 1.0152x over previous
//
#include <hip/hip_runtime.h>
#include <hip/hip_bf16.h>
#include <stdint.h>

#define NN  100000
#define NME 400000
#define NWE 200000
// D = 128, 3D = 384

typedef __bf16 bf16;
typedef __bf16 bf16x8 __attribute__((ext_vector_type(8)));
typedef float  f32x4  __attribute__((ext_vector_type(4)));

static __device__ __forceinline__ bf16 f2bf(float f) {
    union { unsigned int i; float f; } v; v.f = f;
    unsigned int r = (v.i + 0x7fffu + ((v.i >> 16) & 1u)) >> 16;
    union { unsigned short s; bf16 b; } u; u.s = (unsigned short)r;
    return u.b;
}

// ---------------------------------------------------------------------------
// Weight prep: read fp32 W1 (384x128), W2, W3 (128x128); write transposed bf16
// so the MFMA B-fragment (8 consecutive k for fixed n) is a contiguous 16B load.
// ---------------------------------------------------------------------------
__global__ void prep_weights(const float* __restrict__ W1, const float* __restrict__ W2,
                             const float* __restrict__ W3, bf16* __restrict__ W1t,
                             bf16* __restrict__ W2t, bf16* __restrict__ W3t) {
    int tid = blockIdx.x * 256 + threadIdx.x;
    if (tid < 49152) {                    // W1: k in [0,384), n in [0,128)
        int k = tid >> 7, n = tid & 127;
        W1t[n * 384 + k] = f2bf(W1[tid]);
    } else if (tid < 65536) {
        int t2 = tid - 49152;
        int k = t2 >> 7, n = t2 & 127;
        W2t[n * 128 + k] = f2bf(W2[t2]);
    } else if (tid < 81920) {
        int t2 = tid - 65536;
        int k = t2 >> 7, n = t2 & 127;
        W3t[n * 128 + k] = f2bf(W3[t2]);
    }
}

// ---------------------------------------------------------------------------
// CSR build, step 1: per-receiver degree histogram (int atomics, tiny traffic).
// ---------------------------------------------------------------------------
__global__ __launch_bounds__(256) void count_edges(const int* __restrict__ mrecv,
                                                   const int* __restrict__ wrecv,
                                                   int* __restrict__ mdeg,
                                                   int* __restrict__ wdeg) {
    int t = blockIdx.x * 256 + threadIdx.x;
    if (t < NME) {
        atomicAdd(mdeg + mrecv[t], 1);
    } else {
        int t2 = t - NME;
        if (t2 < NWE) atomicAdd(wdeg + wrecv[t2], 1);
    }
}

// ---------------------------------------------------------------------------
// CSR build, step 2a: per-block partial sums. 25 blocks per segment, each
// covering a 4096-int window with coalesced int4 loads.
// ---------------------------------------------------------------------------
__global__ __launch_bounds__(256) void scan_part(const int* __restrict__ mdeg,
                                                 const int* __restrict__ wdeg,
                                                 int* __restrict__ bsum) {
    const int nblk = 25;                      // ceil(100000 / 4096)
    int seg = blockIdx.x / nblk;
    int blk = blockIdx.x % nblk;
    const int* deg = (seg == 0) ? mdeg : wdeg;
    const int t = threadIdx.x;
    const int base = blk * 4096;
    int sum = 0;
#pragma unroll
    for (int i = 0; i < 4; ++i) {
        int idx = base + (i * 256 + t) * 4;   // 16B-aligned; NN % 4 == 0
        if (idx < NN) {
            int4 v = *(const int4*)(deg + idx);
            sum += v.x + v.y + v.z + v.w;
        }
    }
#pragma unroll
    for (int m = 1; m < 64; m <<= 1) sum += __shfl_xor(sum, m, 64);
    __shared__ int ssum[4];
    if ((t & 63) == 0) ssum[t >> 6] = sum;
    __syncthreads();
    if (t == 0) bsum[blockIdx.x] = ssum[0] + ssum[1] + ssum[2] + ssum[3];
}

// ---------------------------------------------------------------------------
// CSR build, step 2b: block-local exclusive scan + block offset, writes
// off (in place over deg) and cur.
// ---------------------------------------------------------------------------
__global__ __launch_bounds__(256) void scan_write(int* __restrict__ mdeg, int* __restrict__ wdeg,
                                                  int* __restrict__ mcur, int* __restrict__ wcur,
                                                  const int* __restrict__ bsum) {
    __shared__ int sprefix;
    __shared__ int sscan[256];
    const int nblk = 25;
    int seg = blockIdx.x / nblk;
    int blk = blockIdx.x % nblk;
    int* deg = (seg == 0) ? mdeg : wdeg;
    int* cur = (seg == 0) ? mcur : wcur;
    const int t = threadIdx.x;
    if (t == 0) {
        int s = 0;
        const int* bs = bsum + seg * nblk;
        for (int i = 0; i < blk; ++i) s += bs[i];
        sprefix = s;
    }
    const int base = blk * 4096 + t * 16;
    int v[16];
#pragma unroll
    for (int i = 0; i < 16; i += 4) {
        int idx = base + i;                   // 16B-aligned; NN % 4 == 0
        if (idx < NN) {
            int4 q = *(const int4*)(deg + idx);
            v[i] = q.x; v[i + 1] = q.y; v[i + 2] = q.z; v[i + 3] = q.w;
        } else {
            v[i] = v[i + 1] = v[i + 2] = v[i + 3] = 0;
        }
    }
    int lsum = 0;
#pragma unroll
    for (int i = 0; i < 16; ++i) lsum += v[i];
    sscan[t] = lsum;
    __syncthreads();
    for (int d = 1; d < 256; d <<= 1) {       // inclusive scan of thread sums
        int vv = (t >= d) ? sscan[t - d] : 0;
        __syncthreads();
        sscan[t] += vv;
        __syncthreads();
    }
    int run = sprefix + sscan[t] - lsum;      // exclusive prefix for this thread
#pragma unroll
    for (int i = 0; i < 16; i += 4) {
        int idx = base + i;
        if (idx < NN) {
            int4 o;
            o.x = run; run += v[i];
            o.y = run; run += v[i + 1];
            o.z = run; run += v[i + 2];
            o.w = run; run += v[i + 3];
            *(int4*)(deg + idx) = o;
            *(int4*)(cur + idx) = o;
        }
    }
}

// ---------------------------------------------------------------------------
// CSR build, step 3: bucket edge ids by receiver (cursor atomics).
// ---------------------------------------------------------------------------
__global__ __launch_bounds__(256) void fill_lists(const int* __restrict__ mrecv,
                                                  const int* __restrict__ wrecv,
                                                  int* __restrict__ mcur, int* __restrict__ wcur,
                                                  int* __restrict__ mlist, int* __restrict__ wlist) {
    int t = blockIdx.x * 256 + threadIdx.x;
    if (t < NME) {
        int r = mrecv[t];
        int p = atomicAdd(mcur + r, 1);
        mlist[p] = t;
    } else {
        int t2 = t - NME;
        if (t2 < NWE) {
            int r = wrecv[t2];
            int p = atomicAdd(wcur + r, 1);
            wlist[p] = t2;
        }
    }
}

// ---------------------------------------------------------------------------
// Fused gather (mesh + world) + x->bf16 convert, one dispatch:
//   blocks [0, 6250)      mesh gather  (quarter-wave per node)
//   blocks [6250, 12500)  world gather
//   blocks [12500, 18750) x fp32 -> bf16 copy (xb), 8 elems/thread
// ---------------------------------------------------------------------------
__global__ __launch_bounds__(256) void gather_sum2(const float* __restrict__ mattr,
                                                   const int* __restrict__ moff,
                                                   const int* __restrict__ mlist,
                                                   bf16* __restrict__ magg,
                                                   const float* __restrict__ wattr,
                                                   const int* __restrict__ woff,
                                                   const int* __restrict__ wlist,
                                                   bf16* __restrict__ wagg,
                                                   const float* __restrict__ x,
                                                   bf16* __restrict__ xb) {
    const int nblk = (NN * 16) / 256;         // 6250 blocks per segment
    if (blockIdx.x >= 2 * nblk) {             // ---- x convert segment ----
        int blk = blockIdx.x - 2 * nblk;
        int base = blk * 2048 + threadIdx.x * 8;   // element index; 12.8M total
        f32x4 lo = *(const f32x4*)(x + base);
        f32x4 hi = *(const f32x4*)(x + base + 4);
        bf16x8 o;
#pragma unroll
        for (int i = 0; i < 4; ++i) {
            o[i]     = f2bf(lo[i]);
            o[4 + i] = f2bf(hi[i]);
        }
        *(bf16x8*)(xb + base) = o;
        return;
    }
    int seg = (blockIdx.x >= nblk);
    int blk = blockIdx.x - seg * nblk;
    const float* attr = seg ? wattr : mattr;
    const int*   off  = seg ? woff  : moff;
    const int*   list = seg ? wlist : mlist;
    bf16*        agg  = seg ? wagg  : magg;
    const int    nE   = seg ? NWE   : NME;

    int t = blk * 256 + threadIdx.x;
    int node = t >> 4;
    int g = t & 15;
    if (node >= NN) return;
    int j0 = off[node];
    int j1 = (node == NN - 1) ? nE : off[node + 1];
    f32x4 lo = (f32x4)0.0f, hi = (f32x4)0.0f;
    for (int j = j0; j < j1; ++j) {
        int e = list[j];
        const float* src = attr + (size_t)e * 128 + g * 8;
        f32x4 a = *(const f32x4*)(src);
        f32x4 b = *(const f32x4*)(src + 4);
        lo += a;
        hi += b;
    }
    bf16x8 o;
#pragma unroll
    for (int i = 0; i < 4; ++i) {
        o[i]     = f2bf(lo[i]);
        o[4 + i] = f2bf(hi[i]);
    }
    *(bf16x8*)(agg + (size_t)node * 128 + g * 8) = o;
}

// ---------------------------------------------------------------------------
// Weight-slice source address for cooperative LDS staging.
// Slices 0..11 = W1t k-slices, 12..15 = W2t, 16..19 = W3t (32 k each, 8 KB).
// ---------------------------------------------------------------------------
static __device__ __forceinline__ const int4* wsrc(const bf16* __restrict__ W1t,
                                                   const bf16* __restrict__ W2t,
                                                   const bf16* __restrict__ W3t,
                                                   int slice, int n, int q) {
    const bf16* W; int ld, kb;
    if (slice < 12)      { W = W1t; ld = 384; kb = slice * 32; }
    else if (slice < 16) { W = W2t; ld = 128; kb = (slice - 12) * 32; }
    else                 { W = W3t; ld = 128; kb = (slice - 16) * 32; }
    return (const int4*)(W + n * ld + kb + q * 8);
}

// A-fragment source for layer-1 slice ks (all bf16 now: xb | magg | wagg).
static __device__ __forceinline__ const bf16x8* asrc(const bf16* __restrict__ xb,
                                                     const bf16* __restrict__ magg,
                                                     const bf16* __restrict__ wagg,
                                                     int ks, int arow, int colq) {
    const bf16* B = (ks < 4) ? xb : (ks < 8 ? magg : wagg);
    return (const bf16x8*)(B + (size_t)arow * 128 + (ks & 3) * 32 + colq);
}

// ---------------------------------------------------------------------------
// Fused node MLP + LayerNorm with cooperative double-buffered LDS weight
// staging AND one-slice-ahead A-fragment prefetch (preA). 256 thr = 4 waves,
// M=32/wave -> 128 nodes/block, 782 blocks, LDS 50.8 KB -> 3 blocks/CU.
// All A operands are bf16 (x pre-converted to xb by gather_sum2), so the
// hot loop has no f32->bf16 cvts and the A global-load latency hides under
// the previous slice's MFMAs + barriers.
// ---------------------------------------------------------------------------
__global__ __launch_bounds__(256) void node_mlp(
    const bf16* __restrict__ xb, const bf16* __restrict__ magg,
    const bf16* __restrict__ wagg, const bf16* __restrict__ W1t,
    const bf16* __restrict__ W2t, const bf16* __restrict__ W3t,
    const float* __restrict__ b1, const float* __restrict__ b2,
    const float* __restrict__ b3, const float* __restrict__ gam,
    const float* __restrict__ bet, float* __restrict__ out) {
    __shared__ bf16 sh_w[2][4096];      // double-buffered 8 KB weight slice
    __shared__ bf16 sh_h[4][32 * 136];  // per-wave h tile (row stride 272 B)
    const int tid  = threadIdx.x;
    const int wave = tid >> 6;
    const int lane = tid & 63;
    const int quad = lane >> 4;
    const int l16  = lane & 15;
    const int node_base = blockIdx.x * 128 + wave * 32;
    bf16* shw = sh_h[wave];

    // staging slots: this thread owns slots tid and tid+256
    const int s0 = tid, s1 = tid + 256;
    const int n0 = ((s0 >> 6) << 4) | (s0 & 15), q0 = (s0 >> 4) & 3;
    const int n1 = ((s1 >> 6) << 4) | (s1 & 15), q1 = (s1 >> 4) & 3;
    int4 st0, st1;

    // prologue: stage slice 0 into buf 0
    st0 = *wsrc(W1t, W2t, W3t, 0, n0, q0);
    st1 = *wsrc(W1t, W2t, W3t, 0, n1, q1);
    *(int4*)(&sh_w[0][s0 * 8]) = st0;
    *(int4*)(&sh_w[0][s1 * 8]) = st1;
    __syncthreads();

    int arow[2];
    arow[0] = node_base + l16;
    arow[1] = node_base + 16 + l16;
    if (arow[0] >= NN) arow[0] = NN - 1;  // clamp; stores are guarded
    if (arow[1] >= NN) arow[1] = NN - 1;

    const int colq = quad * 8;

    f32x4 acc[2][8];
#pragma unroll
    for (int rg = 0; rg < 2; ++rg)
#pragma unroll
        for (int t = 0; t < 8; ++t) acc[rg][t] = (f32x4)0.0f;

    // A prefetch for slice 0
    bf16x8 preA[2];
    preA[0] = *asrc(xb, magg, wagg, 0, arow[0], colq);
    preA[1] = *asrc(xb, magg, wagg, 0, arow[1], colq);

    // ---- Layer 1: [32 x 384] @ [384 x 128], slices 0..11 ----
#pragma unroll
    for (int ks = 0; ks < 12; ++ks) {
        // issue next weight-slice loads (latency hides under MFMAs)
        st0 = *wsrc(W1t, W2t, W3t, ks + 1, n0, q0);
        st1 = *wsrc(W1t, W2t, W3t, ks + 1, n1, q1);
        bf16x8 af0 = preA[0], af1 = preA[1];
        if (ks < 11) {  // issue next A loads (used NEXT slice)
            preA[0] = *asrc(xb, magg, wagg, ks + 1, arow[0], colq);
            preA[1] = *asrc(xb, magg, wagg, ks + 1, arow[1], colq);
        }
        const bf16* wb = sh_w[ks & 1];
#pragma unroll
        for (int t = 0; t < 8; ++t) {
            bf16x8 bfrag = *(const bf16x8*)(wb + t * 512 + lane * 8);
            acc[0][t] = __builtin_amdgcn_mfma_f32_16x16x32_bf16(af0, bfrag, acc[0][t], 0, 0, 0);
            acc[1][t] = __builtin_amdgcn_mfma_f32_16x16x32_bf16(af1, bfrag, acc[1][t], 0, 0, 0);
        }
        __syncthreads();
        *(int4*)(&sh_w[(ks + 1) & 1][s0 * 8]) = st0;
        *(int4*)(&sh_w[(ks + 1) & 1][s1 * 8]) = st1;
        __syncthreads();
    }
    // bias + relu, C-layout -> h tile (wave-local LDS, no barrier needed)
#pragma unroll
    for (int t = 0; t < 8; ++t) {
        float bv = b1[t * 16 + l16];
#pragma unroll
        for (int rg = 0; rg < 2; ++rg)
#pragma unroll
            for (int r = 0; r < 4; ++r) {
                float h = acc[rg][t][r] + bv;
                h = h > 0.0f ? h : 0.0f;
                shw[(rg * 16 + quad * 4 + r) * 136 + t * 16 + l16] = f2bf(h);
            }
    }

    // ---- Layer 2: [32 x 128] @ [128 x 128], slices 12..15 ----
#pragma unroll
    for (int rg = 0; rg < 2; ++rg)
#pragma unroll
        for (int t = 0; t < 8; ++t) acc[rg][t] = (f32x4)0.0f;
#pragma unroll
    for (int ks = 0; ks < 4; ++ks) {
        st0 = *wsrc(W1t, W2t, W3t, 13 + ks, n0, q0);
        st1 = *wsrc(W1t, W2t, W3t, 13 + ks, n1, q1);
        bf16x8 a2[2];
        a2[0] = *(const bf16x8*)(shw + l16 * 136 + ks * 32 + colq);
        a2[1] = *(const bf16x8*)(shw + (16 + l16) * 136 + ks * 32 + colq);
        const bf16* wb = sh_w[ks & 1];   // slice 12+ks lives in buf (12+ks)&1 = ks&1
#pragma unroll
        for (int t = 0; t < 8; ++t) {
            bf16x8 bfrag = *(const bf16x8*)(wb + t * 512 + lane * 8);
            acc[0][t] = __builtin_amdgcn_mfma_f32_16x16x32_bf16(a2[0], bfrag, acc[0][t], 0, 0, 0);
            acc[1][t] = __builtin_amdgcn_mfma_f32_16x16x32_bf16(a2[1], bfrag, acc[1][t], 0, 0, 0);
        }
        __syncthreads();
        *(int4*)(&sh_w[(13 + ks) & 1][s0 * 8]) = st0;
        *(int4*)(&sh_w[(13 + ks) & 1][s1 * 8]) = st1;
        __syncthreads();
    }
#pragma unroll
    for (int t = 0; t < 8; ++t) {
        float bv = b2[t * 16 + l16];
#pragma unroll
        for (int rg = 0; rg < 2; ++rg)
#pragma unroll
            for (int r = 0; r < 4; ++r) {
                float h = acc[rg][t][r] + bv;
                h = h > 0.0f ? h : 0.0f;
                shw[(rg * 16 + quad * 4 + r) * 136 + t * 16 + l16] = f2bf(h);
            }
    }

    // ---- Layer 3: [32 x 128] @ [128 x 128], slices 16..19 (no relu) ----
#pragma unroll
    for (int rg = 0; rg < 2; ++rg)
#pragma unroll
        for (int t = 0; t < 8; ++t) acc[rg][t] = (f32x4)0.0f;
#pragma unroll
    for (int ks = 0; ks < 4; ++ks) {
        if (ks < 3) {
            st0 = *wsrc(W1t, W2t, W3t, 17 + ks, n0, q0);
            st1 = *wsrc(W1t, W2t, W3t, 17 + ks, n1, q1);
        }
        bf16x8 a2[2];
        a2[0] = *(const bf16x8*)(shw + l16 * 136 + ks * 32 + colq);
        a2[1] = *(const bf16x8*)(shw + (16 + l16) * 136 + ks * 32 + colq);
        const bf16* wb = sh_w[ks & 1];   // slice 16+ks in buf (16+ks)&1 = ks&1
#pragma unroll
        for (int t = 0; t < 8; ++t) {
            bf16x8 bfrag = *(const bf16x8*)(wb + t * 512 + lane * 8);
            acc[0][t] = __builtin_amdgcn_mfma_f32_16x16x32_bf16(a2[0], bfrag, acc[0][t], 0, 0, 0);
            acc[1][t] = __builtin_amdgcn_mfma_f32_16x16x32_bf16(a2[1], bfrag, acc[1][t], 0, 0, 0);
        }
        if (ks < 3) {
            __syncthreads();
            *(int4*)(&sh_w[(17 + ks) & 1][s0 * 8]) = st0;
            *(int4*)(&sh_w[(17 + ks) & 1][s1 * 8]) = st1;
            __syncthreads();
        }
    }
    // add b3
#pragma unroll
    for (int t = 0; t < 8; ++t) {
        float bv = b3[t * 16 + l16];
#pragma unroll
        for (int rg = 0; rg < 2; ++rg)
#pragma unroll
            for (int r = 0; r < 4; ++r) acc[rg][t][r] += bv;
    }

    // ---- LayerNorm over the 128 cols of each row ----
    float gv[8], bv2[8];
#pragma unroll
    for (int t = 0; t < 8; ++t) {
        gv[t]  = gam[t * 16 + l16];
        bv2[t] = bet[t * 16 + l16];
    }
#pragma unroll
    for (int rg = 0; rg < 2; ++rg) {
        float mean[4], rstd[4];
#pragma unroll
        for (int r = 0; r < 4; ++r) {
            float s = 0.0f, s2 = 0.0f;
#pragma unroll
            for (int t = 0; t < 8; ++t) {
                float v = acc[rg][t][r];
                s += v;
                s2 += v * v;
            }
#pragma unroll
            for (int m = 1; m < 16; m <<= 1) {
                s  += __shfl_xor(s, m, 64);
                s2 += __shfl_xor(s2, m, 64);
            }
            float mu = s * (1.0f / 128.0f);
            float var = s2 * (1.0f / 128.0f) - mu * mu;
            mean[r] = mu;
            rstd[r] = rsqrtf(var + 1e-5f);
        }
#pragma unroll
        for (int r = 0; r < 4; ++r) {
            int row = node_base + rg * 16 + quad * 4 + r;
            if (row < NN) {
#pragma unroll
                for (int t = 0; t < 8; ++t) {
                    float o = (acc[rg][t][r] - mean[r]) * rstd[r] * gv[t] + bv2[t];
                    out[(size_t)row * 128 + t * 16 + l16] = o;
                }
            }
        }
    }
}

// ---------------------------------------------------------------------------
extern "C" void kernel_launch(void* const* d_in, const int* in_sizes, int n_in,
                              void* d_out, int out_size, void* d_ws, size_t ws_size,
                              hipStream_t stream) {
    const float* x   = (const float*)d_in[0];
    const float* ea  = (const float*)d_in[1];
    const int*   ei  = (const int*)d_in[2];   // (2, NME) flat; recv row at offset NME
    const float* wea = (const float*)d_in[3];
    const int*   wei = (const int*)d_in[4];   // (2, NWE) flat; recv row at offset NWE
    const float* W1  = (const float*)d_in[5];
    const float* b1  = (const float*)d_in[6];
    const float* W2  = (const float*)d_in[7];
    const float* b2  = (const float*)d_in[8];
    const float* W3  = (const float*)d_in[9];
    const float* b3  = (const float*)d_in[10];
    const float* gam = (const float*)d_in[11];
    const float* bet = (const float*)d_in[12];

    char* ws = (char*)d_ws;
    bf16* magg = (bf16*)(ws);                      // 25,600,000 B
    bf16* wagg = (bf16*)(ws + 25600000);           // 25,600,000 B
    bf16* W1t  = (bf16*)(ws + 51200000);           // 98,304 B
    bf16* W2t  = (bf16*)(ws + 51298304);           // 32,768 B
    bf16* W3t  = (bf16*)(ws + 51331072);           // 32,768 B
    int*  mdeg = (int*)(ws + 51363840);            // 400,000 B (deg -> off in place)
    int*  wdeg = (int*)(ws + 51763840);            // 400,000 B (contiguous with mdeg)
    int*  mcur = (int*)(ws + 52163840);            // 400,000 B
    int*  wcur = (int*)(ws + 52563840);            // 400,000 B
    int*  mlist = (int*)(ws + 52963840);           // 1,600,000 B
    int*  wlist = (int*)(ws + 54563840);           // 800,000 B
    int*  bsum  = (int*)(ws + 55363840);           // 256 B (50 block partial sums)
    bf16* xb    = (bf16*)(ws + 55364096);          // 25,600,000 B (x as bf16)

    // zero only the two degree arrays (contiguous 800 KB)
    hipMemsetAsync(ws + 51363840, 0, 800000, stream);

    prep_weights<<<320, 256, 0, stream>>>(W1, W2, W3, W1t, W2t, W3t);

    count_edges<<<(NME + NWE + 255) / 256, 256, 0, stream>>>(ei + NME, wei + NWE, mdeg, wdeg);
    scan_part<<<50, 256, 0, stream>>>(mdeg, wdeg, bsum);
    scan_write<<<50, 256, 0, stream>>>(mdeg, wdeg, mcur, wcur, bsum);
    fill_lists<<<(NME + NWE + 255) / 256, 256, 0, stream>>>(ei + NME, wei + NWE,
                                                            mcur, wcur, mlist, wlist);

    gather_sum2<<<3 * ((NN * 16) / 256), 256, 0, stream>>>(ea, mdeg, mlist, magg,
                                                           wea, wdeg, wlist, wagg,
                                                           x, xb);

    node_mlp<<<(NN + 127) / 128, 256, 0, stream>>>(xb, magg, wagg, W1t, W2t, W3t,
                                                   b1, b2, b3, gam, bet, (float*)d_out);
}